// Round 1
// baseline (476.817 us; speedup 1.0000x reference)
//
#include <hip/hip_runtime.h>
#include <stdint.h>
#include <math.h>

// ---------------------------------------------------------------------------
// Transformer block (B=2, S=2048, D=1024, H=16, hd=64, F=4096), post-LN.
// bf16 MFMA for all matmuls, fp32 accumulate. Threshold is 2% of |ref|max.
// ---------------------------------------------------------------------------

typedef __attribute__((ext_vector_type(4))) float f32x4;
typedef __attribute__((ext_vector_type(8))) short s16x8;

__device__ __forceinline__ float bf2f(short s){
  unsigned u = ((unsigned)(unsigned short)s) << 16;
  return __builtin_bit_cast(float, u);
}
__device__ __forceinline__ short f2bf(float f){
  unsigned u = __builtin_bit_cast(unsigned, f);
  unsigned r = (u + 0x7fffu + ((u >> 16) & 1u)) >> 16;   // RNE
  return (short)(unsigned short)r;
}

__device__ __forceinline__ void gload_lds16(const void* gp, void* lp){
  __builtin_amdgcn_global_load_lds(
      (__attribute__((address_space(1))) void*)const_cast<void*>(gp),
      (__attribute__((address_space(3))) void*)lp,
      16, 0, 0);
}

// ---------------- elementwise f32 -> bf16 ----------------------------------
__global__ void cvt_f32_bf16(const float* __restrict__ in, short* __restrict__ out, int n){
  int i = (blockIdx.x * blockDim.x + threadIdx.x) * 4;
  if (i < n){
    float4 v = *(const float4*)(in + i);
    short4 o;
    o.x = f2bf(v.x); o.y = f2bf(v.y); o.z = f2bf(v.z); o.w = f2bf(v.w);
    *(short4*)(out + i) = o;
  }
}

// ---------------- weight transpose+convert: in[R][C] f32 -> out[C][R] bf16 --
__global__ __launch_bounds__(256) void wtrans(const float* __restrict__ in,
                                              short* __restrict__ out, int R, int C){
  __shared__ float tile[32][33];
  int c0 = blockIdx.x * 32, r0 = blockIdx.y * 32;
  int tx = threadIdx.x, ty = threadIdx.y;        // block (32,8)
  #pragma unroll
  for (int j = 0; j < 4; ++j)
    tile[ty + j*8][tx] = in[(size_t)(r0 + ty + j*8) * C + c0 + tx];
  __syncthreads();
  #pragma unroll
  for (int j = 0; j < 4; ++j)
    out[(size_t)(c0 + ty + j*8) * R + r0 + tx] = f2bf(tile[tx][ty + j*8]);
}

// ---------------- V transpose: qkv[b*2048+s][2048+h*64+d] -> vt[(bh*64+d)][s]
__global__ __launch_bounds__(256) void vtrans(const short* __restrict__ qkv,
                                              short* __restrict__ vt){
  __shared__ short tile[32][33];
  int bh = blockIdx.z; int b = bh >> 4, h = bh & 15;
  int s0 = blockIdx.x * 32, d0 = blockIdx.y * 32;
  int tx = threadIdx.x, ty = threadIdx.y;
  #pragma unroll
  for (int j = 0; j < 4; ++j)
    tile[ty + j*8][tx] = qkv[(size_t)(b*2048 + s0 + ty + j*8) * 3072 + 2048 + h*64 + d0 + tx];
  __syncthreads();
  #pragma unroll
  for (int j = 0; j < 4; ++j)
    vt[(size_t)(bh*64 + d0 + ty + j*8) * 2048 + s0 + tx] = tile[tx][ty + j*8];
}

// ---------------- GEMM: C[M][N] = A[M][K](bf16) @ BT[N][K](bf16)^T + bias ---
// EPI: 0 = store bf16 (qkv)
//      1 = store f32 (acc + bias + aux_f32[row*N+col])          (r1 = x + attn)
//      2 = gelu exact, store bf16                               (fc)
//      3 = store f32 (acc + bias + bf16(aux_bf16[row*N+col]))   (r2 = n + mlp)
#define GBM 128
#define GBN 128
#define GBK 64

__global__ __launch_bounds__(256, 2) void gemm_bf16(
    const short* __restrict__ A, const short* __restrict__ BT,
    const float* __restrict__ bias,
    const float* __restrict__ aux_f32, const short* __restrict__ aux_bf16,
    void* __restrict__ out, int M, int N, int K, int EPI)
{
  __shared__ short sA[GBM * GBK];   // 16 KB, rows of 64 shorts (128 B), XOR-swizzled slots
  __shared__ short sB[GBN * GBK];   // 16 KB
  const int t = threadIdx.x;
  const int lane = t & 63;
  const int w = t >> 6;
  const int wr = w >> 1, wc = w & 1;            // 2x2 wave grid, each wave 64x64
  const int m0 = blockIdx.y * GBM, n0 = blockIdx.x * GBN;
  const int lrow = lane & 15;
  const int lk = lane >> 4;

  f32x4 acc[4][4] = {};

  for (int kk = 0; kk < K; kk += GBK){
    __syncthreads();                            // prior reads done before overwrite
    #pragma unroll
    for (int r = 0; r < 4; ++r){                // stage A: 4 rounds x 4 KB
      int o = r * 4096 + t * 16;                // linear LDS byte offset
      int row = o >> 7;                         // 128 B per row
      int phys = (o >> 4) & 7;                  // 16B slot within row
      int lsl = phys ^ (row & 7);               // inverse-swizzled source chunk
      gload_lds16(A + (size_t)(m0 + row) * K + kk + lsl * 8, (char*)sA + o);
    }
    #pragma unroll
    for (int r = 0; r < 4; ++r){                // stage BT
      int o = r * 4096 + t * 16;
      int row = o >> 7;
      int phys = (o >> 4) & 7;
      int lsl = phys ^ (row & 7);
      gload_lds16(BT + (size_t)(n0 + row) * K + kk + lsl * 8, (char*)sB + o);
    }
    __syncthreads();                            // drains vmcnt before barrier

    #pragma unroll
    for (int kc = 0; kc < 2; ++kc){
      s16x8 af[4], bf[4];
      #pragma unroll
      for (int rt = 0; rt < 4; ++rt){
        int row = wr*64 + rt*16 + lrow;
        int slot = (kc*4 + lk) ^ (row & 7);     // swizzled read
        af[rt] = *(const s16x8*)&sA[row*64 + slot*8];
      }
      #pragma unroll
      for (int ct = 0; ct < 4; ++ct){
        int row = wc*64 + ct*16 + lrow;
        int slot = (kc*4 + lk) ^ (row & 7);
        bf[ct] = *(const s16x8*)&sB[row*64 + slot*8];
      }
      #pragma unroll
      for (int rt = 0; rt < 4; ++rt)
        #pragma unroll
        for (int ct = 0; ct < 4; ++ct)
          acc[rt][ct] = __builtin_amdgcn_mfma_f32_16x16x32_bf16(af[rt], bf[ct], acc[rt][ct], 0, 0, 0);
    }
  }

  #pragma unroll
  for (int rt = 0; rt < 4; ++rt){
    #pragma unroll
    for (int ct = 0; ct < 4; ++ct){
      #pragma unroll
      for (int r = 0; r < 4; ++r){
        int row = m0 + wr*64 + rt*16 + lk*4 + r;    // C/D: row=(lane>>4)*4+reg
        int col = n0 + wc*64 + ct*16 + lrow;        //      col=lane&15
        float v = acc[rt][ct][r] + bias[col];
        size_t idx = (size_t)row * N + col;
        if (EPI == 0){
          ((short*)out)[idx] = f2bf(v);
        } else if (EPI == 1){
          ((float*)out)[idx] = v + aux_f32[idx];
        } else if (EPI == 2){
          float g = 0.5f * v * (1.0f + erff(v * 0.70710678118654752f));
          ((short*)out)[idx] = f2bf(g);
        } else {
          ((float*)out)[idx] = v + bf2f(aux_bf16[idx]);
        }
      }
    }
  }
}

// ---------------- flash attention (causal), 4 waves x 16 q-rows ------------
__global__ __launch_bounds__(256, 2) void attn_kernel(
    const short* __restrict__ qkv, const short* __restrict__ vt,
    short* __restrict__ ob)
{
  const int qt = blockIdx.x;            // q-tile of 64 rows
  const int h  = blockIdx.y;
  const int b  = blockIdx.z;
  const int lane = threadIdx.x & 63;
  const int w = threadIdx.x >> 6;
  const int lrow = lane & 15, lk = lane >> 4;
  const int q0 = qt * 64;
  const int qbase = q0 + w * 16;        // this wave's first q-row

  __shared__ short sP[4][16][68];       // per-wave P tile, +4 shorts pad

  // Q fragments (held in regs for the whole k-loop)
  s16x8 aq[2];
  #pragma unroll
  for (int kc = 0; kc < 2; ++kc)
    aq[kc] = *(const s16x8*)(qkv + (size_t)(b*2048 + qbase + lrow)*3072 + h*64 + kc*32 + lk*8);

  f32x4 oacc[4] = {};
  float mrun[4], lrun[4];
  #pragma unroll
  for (int r = 0; r < 4; ++r){ mrun[r] = -1e30f; lrun[r] = 0.0f; }

  const int ktiles = qt + 1;            // causal: k0 <= q0+63
  for (int ktile = 0; ktile < ktiles; ++ktile){
    const int k0 = ktile * 64;

    // S = Q K^T  (per wave: 16q x 64k)
    f32x4 sacc[4] = {};
    #pragma unroll
    for (int ct = 0; ct < 4; ++ct){
      #pragma unroll
      for (int kc = 0; kc < 2; ++kc){
        s16x8 bk = *(const s16x8*)(qkv + (size_t)(b*2048 + k0 + ct*16 + lrow)*3072
                                   + 1024 + h*64 + kc*32 + lk*8);
        sacc[ct] = __builtin_amdgcn_mfma_f32_16x16x32_bf16(aq[kc], bk, sacc[ct], 0, 0, 0);
      }
    }

    float s[4][4];
    const bool need_mask = (k0 + 63 > qbase);
    #pragma unroll
    for (int ct = 0; ct < 4; ++ct){
      #pragma unroll
      for (int r = 0; r < 4; ++r){
        float v = sacc[ct][r] * 0.125f;               // 1/sqrt(64)
        if (need_mask){
          int qi = qbase + lk*4 + r;
          int ki = k0 + ct*16 + lrow;
          if (ki > qi) v = -10000.0f;                 // reference's mask value
        }
        s[ct][r] = v;
      }
    }

    // online softmax per q-row (row = 16 lanes sharing lk, 4 regs r)
    #pragma unroll
    for (int r = 0; r < 4; ++r){
      float mx = fmaxf(fmaxf(s[0][r], s[1][r]), fmaxf(s[2][r], s[3][r]));
      #pragma unroll
      for (int off = 1; off < 16; off <<= 1)
        mx = fmaxf(mx, __shfl_xor(mx, off, 64));
      float mnew = fmaxf(mrun[r], mx);
      float sf = __expf(mrun[r] - mnew);
      lrun[r] *= sf;
      #pragma unroll
      for (int dt = 0; dt < 4; ++dt) oacc[dt][r] *= sf;
      float ts = 0.0f;
      #pragma unroll
      for (int ct = 0; ct < 4; ++ct){
        float p = __expf(s[ct][r] - mnew);
        s[ct][r] = p;
        ts += p;
      }
      #pragma unroll
      for (int off = 1; off < 16; off <<= 1)
        ts += __shfl_xor(ts, off, 64);
      lrun[r] += ts;
      mrun[r] = mnew;
    }

    // P -> LDS (bf16), wave-private
    #pragma unroll
    for (int ct = 0; ct < 4; ++ct)
      #pragma unroll
      for (int r = 0; r < 4; ++r)
        sP[w][lk*4 + r][ct*16 + lrow] = f2bf(s[ct][r]);

    // O += P V   (A = P[16q][64k], BT = vt[d][k])
    s16x8 pa[2];
    #pragma unroll
    for (int kc = 0; kc < 2; ++kc)
      pa[kc] = *(const s16x8*)&sP[w][lrow][kc*32 + lk*8];
    #pragma unroll
    for (int dt = 0; dt < 4; ++dt){
      #pragma unroll
      for (int kc = 0; kc < 2; ++kc){
        s16x8 bv = *(const s16x8*)(vt + (size_t)((b*16 + h)*64 + dt*16 + lrow)*2048
                                   + k0 + kc*32 + lk*8);
        oacc[dt] = __builtin_amdgcn_mfma_f32_16x16x32_bf16(pa[kc], bv, oacc[dt], 0, 0, 0);
      }
    }
  }

  #pragma unroll
  for (int r = 0; r < 4; ++r){
    float inv = 1.0f / lrun[r];
    int row = b*2048 + qbase + lk*4 + r;
    #pragma unroll
    for (int dt = 0; dt < 4; ++dt){
      int col = h*64 + dt*16 + lrow;
      ob[(size_t)row * 1024 + col] = f2bf(oacc[dt][r] * inv);
    }
  }
}

// ---------------- LayerNorm over D=1024, one block per row -----------------
__global__ __launch_bounds__(256) void ln_kernel(
    const float* __restrict__ in, const float* __restrict__ g,
    const float* __restrict__ b, void* __restrict__ out, int bf16_out)
{
  const int row = blockIdx.x;
  const int t = threadIdx.x;
  float4 v = *(const float4*)(in + (size_t)row*1024 + t*4);
  float s = v.x + v.y + v.z + v.w;
  float q = v.x*v.x + v.y*v.y + v.z*v.z + v.w*v.w;
  #pragma unroll
  for (int off = 1; off < 64; off <<= 1){
    s += __shfl_xor(s, off, 64);
    q += __shfl_xor(q, off, 64);
  }
  __shared__ float ss[4], sq[4];
  if ((t & 63) == 0){ ss[t >> 6] = s; sq[t >> 6] = q; }
  __syncthreads();
  s = ss[0] + ss[1] + ss[2] + ss[3];
  q = sq[0] + sq[1] + sq[2] + sq[3];
  float mu = s * (1.0f/1024.0f);
  float var = q * (1.0f/1024.0f) - mu*mu;
  float rs = rsqrtf(var + 1e-5f);
  float4 gg = *(const float4*)(g + t*4);
  float4 bb = *(const float4*)(b + t*4);
  float o0 = (v.x - mu)*rs*gg.x + bb.x;
  float o1 = (v.y - mu)*rs*gg.y + bb.y;
  float o2 = (v.z - mu)*rs*gg.z + bb.z;
  float o3 = (v.w - mu)*rs*gg.w + bb.w;
  if (bf16_out){
    short4 o; o.x = f2bf(o0); o.y = f2bf(o1); o.z = f2bf(o2); o.w = f2bf(o3);
    *(short4*)((short*)out + (size_t)row*1024 + t*4) = o;
  } else {
    float4 o = {o0, o1, o2, o3};
    *(float4*)((float*)out + (size_t)row*1024 + t*4) = o;
  }
}

// ---------------------------------------------------------------------------
extern "C" void kernel_launch(void* const* d_in, const int* in_sizes, int n_in,
                              void* d_out, int out_size, void* d_ws, size_t ws_size,
                              hipStream_t stream) {
  const float* x      = (const float*)d_in[0];
  const float* w_attn = (const float*)d_in[1];
  const float* b_attn = (const float*)d_in[2];
  const float* w_o    = (const float*)d_in[3];
  const float* b_o    = (const float*)d_in[4];
  const float* ln1_g  = (const float*)d_in[5];
  const float* ln1_b  = (const float*)d_in[6];
  const float* w_fc   = (const float*)d_in[7];
  const float* b_fc   = (const float*)d_in[8];
  const float* w_pr   = (const float*)d_in[9];
  const float* b_pr   = (const float*)d_in[10];
  const float* ln2_g  = (const float*)d_in[11];
  const float* ln2_b  = (const float*)d_in[12];

  char* ws = (char*)d_ws;
  // workspace layout (aliased where lifetimes permit) — total ~96 MB
  short* xb   = (short*)(ws + 0);          // 8 MB  [4096][1024] bf16 (dead after GEMM1)
  short* vt   = (short*)(ws + 0);          // 8 MB  [32*64][2048] bf16 (aliases xb)
  short* waT  = (short*)(ws + 8388608);    // 6 MB  [3072][1024]
  short* woT  = (short*)(ws + 14680064);   // 2 MB  [1024][1024]
  short* wfT  = (short*)(ws + 16777216);   // 8 MB  [4096][1024]
  short* wpT  = (short*)(ws + 25165824);   // 8 MB  [1024][4096]
  short* qkvb = (short*)(ws + 33554432);   // 24 MB [4096][3072] (dead after attn/vtrans)
  short* fb   = (short*)(ws + 33554432);   // 32 MB [4096][4096] (aliases qkvb region)
  short* ob   = (short*)(ws + 67108864);   // 8 MB  [4096][1024]
  float* r1   = (float*)(ws + 75497472);   // 16 MB [4096][1024] f32
  float* r2   = r1;                        //       (aliases r1; r1 dead after LN1)
  short* nb   = (short*)(ws + 92274688);   // 8 MB  [4096][1024]

  const int M = 4096, D = 1024;

  // 1. x -> bf16
  cvt_f32_bf16<<<dim3(M*D/1024), dim3(256), 0, stream>>>(x, xb, M*D);
  // 2-5. weight transposes (f32 [K][N] -> bf16 [N][K])
  wtrans<<<dim3(3072/32, 1024/32), dim3(32,8), 0, stream>>>(w_attn, waT, 1024, 3072);
  wtrans<<<dim3(1024/32, 1024/32), dim3(32,8), 0, stream>>>(w_o,   woT, 1024, 1024);
  wtrans<<<dim3(4096/32, 1024/32), dim3(32,8), 0, stream>>>(w_fc,  wfT, 1024, 4096);
  wtrans<<<dim3(1024/32, 4096/32), dim3(32,8), 0, stream>>>(w_pr,  wpT, 4096, 1024);
  // 6. qkv = x @ w_attn + b_attn  (bf16 out)
  gemm_bf16<<<dim3(3072/GBN, M/GBM), dim3(256), 0, stream>>>(
      xb, waT, b_attn, nullptr, nullptr, qkvb, M, 3072, 1024, 0);
  // 7. vt = transpose of V per (b,h)
  vtrans<<<dim3(2048/32, 64/32, 32), dim3(32,8), 0, stream>>>(qkvb, vt);
  // 8. attention -> ob (bf16)
  attn_kernel<<<dim3(32, 16, 2), dim3(256), 0, stream>>>(qkvb, vt, ob);
  // 9. r1 = x + (o @ w_o + b_o)   (f32 out)
  gemm_bf16<<<dim3(1024/GBN, M/GBM), dim3(256), 0, stream>>>(
      ob, woT, b_o, x, nullptr, r1, M, 1024, 1024, 1);
  // 10. n = LN(r1) -> nb (bf16)
  ln_kernel<<<dim3(M), dim3(256), 0, stream>>>(r1, ln1_g, ln1_b, nb, 1);
  // 11. f = gelu(n @ w_fc + b_fc) -> fb (bf16)
  gemm_bf16<<<dim3(4096/GBN, M/GBM), dim3(256), 0, stream>>>(
      nb, wfT, b_fc, nullptr, nullptr, fb, M, 4096, 1024, 2);
  // 12. r2 = n + (f @ w_pr + b_pr)  (f32 out)
  gemm_bf16<<<dim3(1024/GBN, M/GBM), dim3(256), 0, stream>>>(
      fb, wpT, b_pr, nullptr, nb, r2, M, 1024, 4096, 3);
  // 13. h = LN(r2) -> d_out (f32)
  ln_kernel<<<dim3(M), dim3(256), 0, stream>>>(r2, ln2_g, ln2_b, d_out, 0);
}

// Round 2
// 329.386 us; speedup vs baseline: 1.4476x; 1.4476x over previous
//
#include <hip/hip_runtime.h>
#include <stdint.h>
#include <math.h>

// ---------------------------------------------------------------------------
// Transformer block (B=2, S=2048, D=1024, H=16, hd=64, F=4096), post-LN.
// bf16 MFMA for all matmuls, fp32 accumulate. Threshold is 2% of |ref|max.
// ---------------------------------------------------------------------------

typedef __attribute__((ext_vector_type(4))) float f32x4;
typedef __attribute__((ext_vector_type(8))) short s16x8;

__device__ __forceinline__ float bf2f(short s){
  unsigned u = ((unsigned)(unsigned short)s) << 16;
  return __builtin_bit_cast(float, u);
}
__device__ __forceinline__ short f2bf(float f){
  unsigned u = __builtin_bit_cast(unsigned, f);
  unsigned r = (u + 0x7fffu + ((u >> 16) & 1u)) >> 16;   // RNE
  return (short)(unsigned short)r;
}

__device__ __forceinline__ void gload_lds16(const void* gp, void* lp){
  __builtin_amdgcn_global_load_lds(
      (__attribute__((address_space(1))) void*)const_cast<void*>(gp),
      (__attribute__((address_space(3))) void*)lp,
      16, 0, 0);
}

// ---------------- elementwise f32 -> bf16 ----------------------------------
__global__ void cvt_f32_bf16(const float* __restrict__ in, short* __restrict__ out, int n){
  int i = (blockIdx.x * blockDim.x + threadIdx.x) * 4;
  if (i < n){
    float4 v = *(const float4*)(in + i);
    short4 o;
    o.x = f2bf(v.x); o.y = f2bf(v.y); o.z = f2bf(v.z); o.w = f2bf(v.w);
    *(short4*)(out + i) = o;
  }
}

// ---------------- weight transpose+convert: in[R][C] f32 -> out[C][R] bf16 --
__global__ __launch_bounds__(256) void wtrans(const float* __restrict__ in,
                                              short* __restrict__ out, int R, int C){
  __shared__ float tile[32][33];
  int c0 = blockIdx.x * 32, r0 = blockIdx.y * 32;
  int tx = threadIdx.x, ty = threadIdx.y;        // block (32,8)
  #pragma unroll
  for (int j = 0; j < 4; ++j)
    tile[ty + j*8][tx] = in[(size_t)(r0 + ty + j*8) * C + c0 + tx];
  __syncthreads();
  #pragma unroll
  for (int j = 0; j < 4; ++j)
    out[(size_t)(c0 + ty + j*8) * R + r0 + tx] = f2bf(tile[tx][ty + j*8]);
}

// ---------------- V transpose: qkv[b*2048+s][2048+h*64+d] -> vt[(bh*64+d)][s]
__global__ __launch_bounds__(256) void vtrans(const short* __restrict__ qkv,
                                              short* __restrict__ vt){
  __shared__ short tile[32][33];
  int bh = blockIdx.z; int b = bh >> 4, h = bh & 15;
  int s0 = blockIdx.x * 32, d0 = blockIdx.y * 32;
  int tx = threadIdx.x, ty = threadIdx.y;
  #pragma unroll
  for (int j = 0; j < 4; ++j)
    tile[ty + j*8][tx] = qkv[(size_t)(b*2048 + s0 + ty + j*8) * 3072 + 2048 + h*64 + d0 + tx];
  __syncthreads();
  #pragma unroll
  for (int j = 0; j < 4; ++j)
    vt[(size_t)(bh*64 + d0 + ty + j*8) * 2048 + s0 + tx] = tile[tx][ty + j*8];
}

// ---------------- GEMM: C[M][N] = A[M][K](bf16) @ BT[N][K](bf16)^T + bias ---
// EPI: 0 = store bf16 (qkv)
//      1 = store f32 (acc + bias + aux_f32[row*N+col])          (r1 = x + attn)
//      2 = gelu exact, store bf16                               (fc)
//      3 = store f32 (acc + bias + bf16(aux_bf16[row*N+col]))   (r2 = n + mlp)
#define GBM 128
#define GBN 128
#define GBK 64

__global__ __launch_bounds__(256, 2) void gemm_bf16(
    const short* __restrict__ A, const short* __restrict__ BT,
    const float* __restrict__ bias,
    const float* __restrict__ aux_f32, const short* __restrict__ aux_bf16,
    void* __restrict__ out, int M, int N, int K, int EPI)
{
  __shared__ short sA[GBM * GBK];   // 16 KB, rows of 64 shorts (128 B), XOR-swizzled slots
  __shared__ short sB[GBN * GBK];   // 16 KB
  const int t = threadIdx.x;
  const int lane = t & 63;
  const int w = t >> 6;
  const int wr = w >> 1, wc = w & 1;            // 2x2 wave grid, each wave 64x64
  const int m0 = blockIdx.y * GBM, n0 = blockIdx.x * GBN;
  const int lrow = lane & 15;
  const int lk = lane >> 4;

  f32x4 acc[4][4] = {};

  for (int kk = 0; kk < K; kk += GBK){
    __syncthreads();                            // prior reads done before overwrite
    #pragma unroll
    for (int r = 0; r < 4; ++r){                // stage A: 4 rounds x 4 KB
      int o = r * 4096 + t * 16;                // linear LDS byte offset
      int row = o >> 7;                         // 128 B per row
      int phys = (o >> 4) & 7;                  // 16B slot within row
      int lsl = phys ^ (row & 7);               // inverse-swizzled source chunk
      gload_lds16(A + (size_t)(m0 + row) * K + kk + lsl * 8, (char*)sA + o);
    }
    #pragma unroll
    for (int r = 0; r < 4; ++r){                // stage BT
      int o = r * 4096 + t * 16;
      int row = o >> 7;
      int phys = (o >> 4) & 7;
      int lsl = phys ^ (row & 7);
      gload_lds16(BT + (size_t)(n0 + row) * K + kk + lsl * 8, (char*)sB + o);
    }
    __syncthreads();                            // drains vmcnt before barrier

    #pragma unroll
    for (int kc = 0; kc < 2; ++kc){
      s16x8 af[4], bf[4];
      #pragma unroll
      for (int rt = 0; rt < 4; ++rt){
        int row = wr*64 + rt*16 + lrow;
        int slot = (kc*4 + lk) ^ (row & 7);     // swizzled read
        af[rt] = *(const s16x8*)&sA[row*64 + slot*8];
      }
      #pragma unroll
      for (int ct = 0; ct < 4; ++ct){
        int row = wc*64 + ct*16 + lrow;
        int slot = (kc*4 + lk) ^ (row & 7);
        bf[ct] = *(const s16x8*)&sB[row*64 + slot*8];
      }
      #pragma unroll
      for (int rt = 0; rt < 4; ++rt)
        #pragma unroll
        for (int ct = 0; ct < 4; ++ct)
          acc[rt][ct] = __builtin_amdgcn_mfma_f32_16x16x32_bf16(af[rt], bf[ct], acc[rt][ct], 0, 0, 0);
    }
  }

  #pragma unroll
  for (int rt = 0; rt < 4; ++rt){
    #pragma unroll
    for (int ct = 0; ct < 4; ++ct){
      #pragma unroll
      for (int r = 0; r < 4; ++r){
        int row = m0 + wr*64 + rt*16 + lk*4 + r;    // C/D: row=(lane>>4)*4+reg
        int col = n0 + wc*64 + ct*16 + lrow;        //      col=lane&15
        float v = acc[rt][ct][r] + bias[col];
        size_t idx = (size_t)row * N + col;
        if (EPI == 0){
          ((short*)out)[idx] = f2bf(v);
        } else if (EPI == 1){
          ((float*)out)[idx] = v + aux_f32[idx];
        } else if (EPI == 2){
          float g = 0.5f * v * (1.0f + erff(v * 0.70710678118654752f));
          ((short*)out)[idx] = f2bf(g);
        } else {
          ((float*)out)[idx] = v + bf2f(aux_bf16[idx]);
        }
      }
    }
  }
}

// ---------------- flash attention (causal), LDS-staged K/V, paired q-tiles --
// Block = 4 waves; wave w owns q-rows [qt*64 + w*16, +16). Each block handles
// q-tile `pair` then q-tile `31-pair` -> every block does exactly 33 k-tiles.
__global__ __launch_bounds__(256, 2) void attn_kernel(
    const short* __restrict__ qkv, const short* __restrict__ vt,
    short* __restrict__ ob)
{
  const int pairi = blockIdx.x;         // 0..15
  const int h  = blockIdx.y;
  const int b  = blockIdx.z;
  const int t  = threadIdx.x;
  const int lane = t & 63;
  const int w = t >> 6;
  const int lrow = lane & 15, lk = lane >> 4;

  __shared__ short sK[2][64*64];        // 2 x 8 KB, rows of 64 shorts, XOR-swizzled
  __shared__ short sV[2][64*64];        // 2 x 8 KB
  __shared__ short sP[4][16][68];       // per-wave P tile, +4 shorts pad

  const size_t kgbase = (size_t)(b*2048)*3072 + 1024 + h*64;   // K rows in qkv
  const size_t vgbase = (size_t)((b*16 + h)*64)*2048;          // V^T rows in vt

  auto stage = [&](int buf, int k0){
    #pragma unroll
    for (int r2 = 0; r2 < 2; ++r2){     // 8 KB per tile: 2 rounds x 4 KB
      int o = r2*4096 + t*16;           // linear LDS byte offset
      int row = o >> 7;                 // 128 B per row
      int lsl = ((o >> 4) & 7) ^ (row & 7);   // inverse-swizzled source chunk
      gload_lds16(qkv + kgbase + (size_t)(k0 + row)*3072 + lsl*8, (char*)sK[buf] + o);
      gload_lds16(vt  + vgbase + (size_t)row*2048 + k0   + lsl*8, (char*)sV[buf] + o);
    }
  };

  for (int pass = 0; pass < 2; ++pass){
    const int qt = pass ? 31 - pairi : pairi;
    const int q0 = qt * 64;
    const int qbase = q0 + w * 16;

    // Q fragments (held in regs for the whole k-loop)
    s16x8 aq[2];
    #pragma unroll
    for (int kc = 0; kc < 2; ++kc)
      aq[kc] = *(const s16x8*)(qkv + (size_t)(b*2048 + qbase + lrow)*3072 + h*64 + kc*32 + lk*8);

    f32x4 oacc[4] = {};
    float mrun[4], lrun[4];
    #pragma unroll
    for (int r = 0; r < 4; ++r){ mrun[r] = -1e30f; lrun[r] = 0.0f; }

    const int nt = qt + 1;
    __syncthreads();                    // prior pass's reads complete
    stage(0, 0);                        // prologue
    __syncthreads();
    int cur = 0;

    for (int ktile = 0; ktile < nt; ++ktile){
      const int k0 = ktile * 64;
      if (ktile + 1 < nt) stage(cur ^ 1, k0 + 64);   // prefetch next tile

      // S = Q K^T  (per wave: 16q x 64k), K from LDS
      f32x4 sacc[4] = {};
      #pragma unroll
      for (int kc = 0; kc < 2; ++kc){
        #pragma unroll
        for (int ct = 0; ct < 4; ++ct){
          int row = ct*16 + lrow;
          int slot = (kc*4 + lk) ^ (row & 7);
          s16x8 bk = *(const s16x8*)&sK[cur][row*64 + slot*8];
          sacc[ct] = __builtin_amdgcn_mfma_f32_16x16x32_bf16(aq[kc], bk, sacc[ct], 0, 0, 0);
        }
      }

      float s[4][4];
      const bool need_mask = (k0 + 63 > qbase);
      #pragma unroll
      for (int ct = 0; ct < 4; ++ct){
        #pragma unroll
        for (int r = 0; r < 4; ++r){
          float v = sacc[ct][r] * 0.125f;               // 1/sqrt(64)
          if (need_mask){
            int qi = qbase + lk*4 + r;
            int ki = k0 + ct*16 + lrow;
            if (ki > qi) v = -10000.0f;                 // reference's mask value
          }
          s[ct][r] = v;
        }
      }

      // online softmax per q-row (row spread over 16 lanes sharing lk)
      #pragma unroll
      for (int r = 0; r < 4; ++r){
        float mx = fmaxf(fmaxf(s[0][r], s[1][r]), fmaxf(s[2][r], s[3][r]));
        #pragma unroll
        for (int off = 1; off < 16; off <<= 1)
          mx = fmaxf(mx, __shfl_xor(mx, off, 64));
        float mnew = fmaxf(mrun[r], mx);
        float sf = __expf(mrun[r] - mnew);
        lrun[r] *= sf;
        #pragma unroll
        for (int dt = 0; dt < 4; ++dt) oacc[dt][r] *= sf;
        float ts = 0.0f;
        #pragma unroll
        for (int ct = 0; ct < 4; ++ct){
          float p = __expf(s[ct][r] - mnew);
          s[ct][r] = p;
          ts += p;
        }
        #pragma unroll
        for (int off = 1; off < 16; off <<= 1)
          ts += __shfl_xor(ts, off, 64);
        lrun[r] += ts;
        mrun[r] = mnew;
      }

      // P -> LDS (bf16), wave-private
      #pragma unroll
      for (int ct = 0; ct < 4; ++ct)
        #pragma unroll
        for (int r = 0; r < 4; ++r)
          sP[w][lk*4 + r][ct*16 + lrow] = f2bf(s[ct][r]);

      // O += P V   (A = P[16q][64k], B^T = V^T[d][k] from LDS)
      s16x8 pa[2];
      #pragma unroll
      for (int kc = 0; kc < 2; ++kc)
        pa[kc] = *(const s16x8*)&sP[w][lrow][kc*32 + lk*8];
      #pragma unroll
      for (int dt = 0; dt < 4; ++dt){
        #pragma unroll
        for (int kc = 0; kc < 2; ++kc){
          int row = dt*16 + lrow;
          int slot = (kc*4 + lk) ^ (row & 7);
          s16x8 bv = *(const s16x8*)&sV[cur][row*64 + slot*8];
          oacc[dt] = __builtin_amdgcn_mfma_f32_16x16x32_bf16(pa[kc], bv, oacc[dt], 0, 0, 0);
        }
      }

      __syncthreads();                  // all waves done with `cur`; prefetch drained
      cur ^= 1;
    }

    #pragma unroll
    for (int r = 0; r < 4; ++r){
      float inv = 1.0f / lrun[r];
      int row = b*2048 + qbase + lk*4 + r;
      #pragma unroll
      for (int dt = 0; dt < 4; ++dt){
        int col = h*64 + dt*16 + lrow;
        ob[(size_t)row * 1024 + col] = f2bf(oacc[dt][r] * inv);
      }
    }
  }
}

// ---------------- LayerNorm over D=1024, one block per row -----------------
__global__ __launch_bounds__(256) void ln_kernel(
    const float* __restrict__ in, const float* __restrict__ g,
    const float* __restrict__ b, void* __restrict__ out, int bf16_out)
{
  const int row = blockIdx.x;
  const int t = threadIdx.x;
  float4 v = *(const float4*)(in + (size_t)row*1024 + t*4);
  float s = v.x + v.y + v.z + v.w;
  float q = v.x*v.x + v.y*v.y + v.z*v.z + v.w*v.w;
  #pragma unroll
  for (int off = 1; off < 64; off <<= 1){
    s += __shfl_xor(s, off, 64);
    q += __shfl_xor(q, off, 64);
  }
  __shared__ float ss[4], sq[4];
  if ((t & 63) == 0){ ss[t >> 6] = s; sq[t >> 6] = q; }
  __syncthreads();
  s = ss[0] + ss[1] + ss[2] + ss[3];
  q = sq[0] + sq[1] + sq[2] + sq[3];
  float mu = s * (1.0f/1024.0f);
  float var = q * (1.0f/1024.0f) - mu*mu;
  float rs = rsqrtf(var + 1e-5f);
  float4 gg = *(const float4*)(g + t*4);
  float4 bb = *(const float4*)(b + t*4);
  float o0 = (v.x - mu)*rs*gg.x + bb.x;
  float o1 = (v.y - mu)*rs*gg.y + bb.y;
  float o2 = (v.z - mu)*rs*gg.z + bb.z;
  float o3 = (v.w - mu)*rs*gg.w + bb.w;
  if (bf16_out){
    short4 o; o.x = f2bf(o0); o.y = f2bf(o1); o.z = f2bf(o2); o.w = f2bf(o3);
    *(short4*)((short*)out + (size_t)row*1024 + t*4) = o;
  } else {
    float4 o = {o0, o1, o2, o3};
    *(float4*)((float*)out + (size_t)row*1024 + t*4) = o;
  }
}

// ---------------------------------------------------------------------------
extern "C" void kernel_launch(void* const* d_in, const int* in_sizes, int n_in,
                              void* d_out, int out_size, void* d_ws, size_t ws_size,
                              hipStream_t stream) {
  const float* x      = (const float*)d_in[0];
  const float* w_attn = (const float*)d_in[1];
  const float* b_attn = (const float*)d_in[2];
  const float* w_o    = (const float*)d_in[3];
  const float* b_o    = (const float*)d_in[4];
  const float* ln1_g  = (const float*)d_in[5];
  const float* ln1_b  = (const float*)d_in[6];
  const float* w_fc   = (const float*)d_in[7];
  const float* b_fc   = (const float*)d_in[8];
  const float* w_pr   = (const float*)d_in[9];
  const float* b_pr   = (const float*)d_in[10];
  const float* ln2_g  = (const float*)d_in[11];
  const float* ln2_b  = (const float*)d_in[12];

  char* ws = (char*)d_ws;
  // workspace layout (aliased where lifetimes permit) — total ~96 MB
  short* xb   = (short*)(ws + 0);          // 8 MB  [4096][1024] bf16 (dead after GEMM1)
  short* vt   = (short*)(ws + 0);          // 8 MB  [32*64][2048] bf16 (aliases xb)
  short* waT  = (short*)(ws + 8388608);    // 6 MB  [3072][1024]
  short* woT  = (short*)(ws + 14680064);   // 2 MB  [1024][1024]
  short* wfT  = (short*)(ws + 16777216);   // 8 MB  [4096][1024]
  short* wpT  = (short*)(ws + 25165824);   // 8 MB  [1024][4096]
  short* qkvb = (short*)(ws + 33554432);   // 24 MB [4096][3072] (dead after attn/vtrans)
  short* fb   = (short*)(ws + 33554432);   // 32 MB [4096][4096] (aliases qkvb region)
  short* ob   = (short*)(ws + 67108864);   // 8 MB  [4096][1024]
  float* r1   = (float*)(ws + 75497472);   // 16 MB [4096][1024] f32
  float* r2   = r1;                        //       (aliases r1; r1 dead after LN1)
  short* nb   = (short*)(ws + 92274688);   // 8 MB  [4096][1024]

  const int M = 4096, D = 1024;

  // 1. x -> bf16
  cvt_f32_bf16<<<dim3(M*D/1024), dim3(256), 0, stream>>>(x, xb, M*D);
  // 2-5. weight transposes (f32 [K][N] -> bf16 [N][K])
  wtrans<<<dim3(3072/32, 1024/32), dim3(32,8), 0, stream>>>(w_attn, waT, 1024, 3072);
  wtrans<<<dim3(1024/32, 1024/32), dim3(32,8), 0, stream>>>(w_o,   woT, 1024, 1024);
  wtrans<<<dim3(4096/32, 1024/32), dim3(32,8), 0, stream>>>(w_fc,  wfT, 1024, 4096);
  wtrans<<<dim3(1024/32, 4096/32), dim3(32,8), 0, stream>>>(w_pr,  wpT, 4096, 1024);
  // 6. qkv = x @ w_attn + b_attn  (bf16 out)
  gemm_bf16<<<dim3(3072/GBN, M/GBM), dim3(256), 0, stream>>>(
      xb, waT, b_attn, nullptr, nullptr, qkvb, M, 3072, 1024, 0);
  // 7. vt = transpose of V per (b,h)
  vtrans<<<dim3(2048/32, 64/32, 32), dim3(32,8), 0, stream>>>(qkvb, vt);
  // 8. attention -> ob (bf16)
  attn_kernel<<<dim3(16, 16, 2), dim3(256), 0, stream>>>(qkvb, vt, ob);
  // 9. r1 = x + (o @ w_o + b_o)   (f32 out)
  gemm_bf16<<<dim3(1024/GBN, M/GBM), dim3(256), 0, stream>>>(
      ob, woT, b_o, x, nullptr, r1, M, 1024, 1024, 1);
  // 10. n = LN(r1) -> nb (bf16)
  ln_kernel<<<dim3(M), dim3(256), 0, stream>>>(r1, ln1_g, ln1_b, nb, 1);
  // 11. f = gelu(n @ w_fc + b_fc) -> fb (bf16)
  gemm_bf16<<<dim3(4096/GBN, M/GBM), dim3(256), 0, stream>>>(
      nb, wfT, b_fc, nullptr, nullptr, fb, M, 4096, 1024, 2);
  // 12. r2 = n + (f @ w_pr + b_pr)  (f32 out)
  gemm_bf16<<<dim3(1024/GBN, M/GBM), dim3(256), 0, stream>>>(
      fb, wpT, b_pr, nullptr, nb, r2, M, 1024, 4096, 3);
  // 13. h = LN(r2) -> d_out (f32)
  ln_kernel<<<dim3(M), dim3(256), 0, stream>>>(r2, ln2_g, ln2_b, d_out, 0);
}

// Round 3
// 312.606 us; speedup vs baseline: 1.5253x; 1.0537x over previous
//
#include <hip/hip_runtime.h>
#include <stdint.h>
#include <math.h>

// ---------------------------------------------------------------------------
// Transformer block (B=2, S=2048, D=1024, H=16, hd=64, F=4096), post-LN.
// bf16 MFMA for all matmuls, fp32 accumulate. Threshold is 2% of |ref|max.
// ---------------------------------------------------------------------------

typedef __attribute__((ext_vector_type(4))) float f32x4;
typedef __attribute__((ext_vector_type(8))) short s16x8;

__device__ __forceinline__ float bf2f(short s){
  unsigned u = ((unsigned)(unsigned short)s) << 16;
  return __builtin_bit_cast(float, u);
}
__device__ __forceinline__ short f2bf(float f){
  unsigned u = __builtin_bit_cast(unsigned, f);
  unsigned r = (u + 0x7fffu + ((u >> 16) & 1u)) >> 16;   // RNE
  return (short)(unsigned short)r;
}

__device__ __forceinline__ void gload_lds16(const void* gp, void* lp){
  __builtin_amdgcn_global_load_lds(
      (__attribute__((address_space(1))) void*)const_cast<void*>(gp),
      (__attribute__((address_space(3))) void*)lp,
      16, 0, 0);
}

// ---------------- elementwise f32 -> bf16 ----------------------------------
__global__ void cvt_f32_bf16(const float* __restrict__ in, short* __restrict__ out, int n){
  int i = (blockIdx.x * blockDim.x + threadIdx.x) * 4;
  if (i < n){
    float4 v = *(const float4*)(in + i);
    short4 o;
    o.x = f2bf(v.x); o.y = f2bf(v.y); o.z = f2bf(v.z); o.w = f2bf(v.w);
    *(short4*)(out + i) = o;
  }
}

// ---------------- weight transpose+convert: in[R][C] f32 -> out[C][R] bf16 --
__global__ __launch_bounds__(256) void wtrans(const float* __restrict__ in,
                                              short* __restrict__ out, int R, int C){
  __shared__ float tile[32][33];
  int c0 = blockIdx.x * 32, r0 = blockIdx.y * 32;
  int tx = threadIdx.x, ty = threadIdx.y;        // block (32,8)
  #pragma unroll
  for (int j = 0; j < 4; ++j)
    tile[ty + j*8][tx] = in[(size_t)(r0 + ty + j*8) * C + c0 + tx];
  __syncthreads();
  #pragma unroll
  for (int j = 0; j < 4; ++j)
    out[(size_t)(c0 + ty + j*8) * R + r0 + tx] = f2bf(tile[tx][ty + j*8]);
}

// ---------------- V transpose: qkv[b*2048+s][2048+h*64+d] -> vt[(bh*64+d)][s]
__global__ __launch_bounds__(256) void vtrans(const short* __restrict__ qkv,
                                              short* __restrict__ vt){
  __shared__ short tile[32][33];
  int bh = blockIdx.z; int b = bh >> 4, h = bh & 15;
  int s0 = blockIdx.x * 32, d0 = blockIdx.y * 32;
  int tx = threadIdx.x, ty = threadIdx.y;
  #pragma unroll
  for (int j = 0; j < 4; ++j)
    tile[ty + j*8][tx] = qkv[(size_t)(b*2048 + s0 + ty + j*8) * 3072 + 2048 + h*64 + d0 + tx];
  __syncthreads();
  #pragma unroll
  for (int j = 0; j < 4; ++j)
    vt[(size_t)(bh*64 + d0 + ty + j*8) * 2048 + s0 + tx] = tile[tx][ty + j*8];
}

// ---------------- GEMM: C[M][N] = A[M][K](bf16) @ BT[N][K](bf16)^T ---------
// EPI: 0 = store bf16 (acc + bias)                              (qkv)
//      1 = store f32 (acc + bias + aux_f32[row*N+col])          (r1 = x + attn)
//      2 = gelu exact on acc + bias, store bf16                 (fc)
//      4 = raw f32 partial to (z==0 ? out : out2)               (split-K)
#define GBM 128
#define GBN 128
#define GBK 64

__global__ __launch_bounds__(256, 2) void gemm_bf16(
    const short* __restrict__ A, const short* __restrict__ BT,
    const float* __restrict__ bias, const float* __restrict__ aux_f32,
    void* __restrict__ out, void* __restrict__ out2,
    int M, int N, int K, int EPI, int KS)
{
  __shared__ short sA[GBM * GBK];   // 16 KB, rows of 64 shorts (128 B), XOR-swizzled slots
  __shared__ short sB[GBN * GBK];   // 16 KB
  const int t = threadIdx.x;
  const int lane = t & 63;
  const int w = t >> 6;
  const int wr = w >> 1, wc = w & 1;            // 2x2 wave grid, each wave 64x64
  const int m0 = blockIdx.y * GBM, n0 = blockIdx.x * GBN;
  const int lrow = lane & 15;
  const int lk = lane >> 4;

  const int Kspl = K / KS;
  const int kbeg = blockIdx.z * Kspl;

  f32x4 acc[4][4] = {};

  for (int kk = kbeg; kk < kbeg + Kspl; kk += GBK){
    __syncthreads();                            // prior reads done before overwrite
    #pragma unroll
    for (int r = 0; r < 4; ++r){                // stage A: 4 rounds x 4 KB
      int o = r * 4096 + t * 16;                // linear LDS byte offset
      int row = o >> 7;                         // 128 B per row
      int phys = (o >> 4) & 7;                  // 16B slot within row
      int lsl = phys ^ (row & 7);               // inverse-swizzled source chunk
      gload_lds16(A + (size_t)(m0 + row) * K + kk + lsl * 8, (char*)sA + o);
    }
    #pragma unroll
    for (int r = 0; r < 4; ++r){                // stage BT
      int o = r * 4096 + t * 16;
      int row = o >> 7;
      int phys = (o >> 4) & 7;
      int lsl = phys ^ (row & 7);
      gload_lds16(BT + (size_t)(n0 + row) * K + kk + lsl * 8, (char*)sB + o);
    }
    __syncthreads();                            // drains vmcnt before barrier

    #pragma unroll
    for (int kc = 0; kc < 2; ++kc){
      s16x8 af[4], bf[4];
      #pragma unroll
      for (int rt = 0; rt < 4; ++rt){
        int row = wr*64 + rt*16 + lrow;
        int slot = (kc*4 + lk) ^ (row & 7);     // swizzled read
        af[rt] = *(const s16x8*)&sA[row*64 + slot*8];
      }
      #pragma unroll
      for (int ct = 0; ct < 4; ++ct){
        int row = wc*64 + ct*16 + lrow;
        int slot = (kc*4 + lk) ^ (row & 7);
        bf[ct] = *(const s16x8*)&sB[row*64 + slot*8];
      }
      #pragma unroll
      for (int rt = 0; rt < 4; ++rt)
        #pragma unroll
        for (int ct = 0; ct < 4; ++ct)
          acc[rt][ct] = __builtin_amdgcn_mfma_f32_16x16x32_bf16(af[rt], bf[ct], acc[rt][ct], 0, 0, 0);
    }
  }

  float* pout = (float*)(blockIdx.z ? out2 : out);
  #pragma unroll
  for (int rt = 0; rt < 4; ++rt){
    #pragma unroll
    for (int ct = 0; ct < 4; ++ct){
      #pragma unroll
      for (int r = 0; r < 4; ++r){
        int row = m0 + wr*64 + rt*16 + lk*4 + r;    // C/D: row=(lane>>4)*4+reg
        int col = n0 + wc*64 + ct*16 + lrow;        //      col=lane&15
        size_t idx = (size_t)row * N + col;
        if (EPI == 4){
          pout[idx] = acc[rt][ct][r];
        } else {
          float v = acc[rt][ct][r] + bias[col];
          if (EPI == 0){
            ((short*)out)[idx] = f2bf(v);
          } else if (EPI == 1){
            ((float*)out)[idx] = v + aux_f32[idx];
          } else {
            float g = 0.5f * v * (1.0f + erff(v * 0.70710678118654752f));
            ((short*)out)[idx] = f2bf(g);
          }
        }
      }
    }
  }
}

// ---------------- flash attention (causal), LDS-staged K/V, paired q-tiles --
// Block = 4 waves; wave w owns q-rows [qt*64 + w*16, +16). Each block handles
// q-tile `pair` then q-tile `31-pair` -> every block does exactly 33 k-tiles.
__global__ __launch_bounds__(256, 2) void attn_kernel(
    const short* __restrict__ qkv, const short* __restrict__ vt,
    short* __restrict__ ob)
{
  const int pairi = blockIdx.x;         // 0..15
  const int h  = blockIdx.y;
  const int b  = blockIdx.z;
  const int t  = threadIdx.x;
  const int lane = t & 63;
  const int w = t >> 6;
  const int lrow = lane & 15, lk = lane >> 4;

  __shared__ short sK[2][64*64];        // 2 x 8 KB, rows of 64 shorts, XOR-swizzled
  __shared__ short sV[2][64*64];        // 2 x 8 KB
  __shared__ short sP[4][16][68];       // per-wave P tile, +4 shorts pad

  const size_t kgbase = (size_t)(b*2048)*3072 + 1024 + h*64;   // K rows in qkv
  const size_t vgbase = (size_t)((b*16 + h)*64)*2048;          // V^T rows in vt

  auto stage = [&](int buf, int k0){
    #pragma unroll
    for (int r2 = 0; r2 < 2; ++r2){     // 8 KB per tile: 2 rounds x 4 KB
      int o = r2*4096 + t*16;           // linear LDS byte offset
      int row = o >> 7;                 // 128 B per row
      int lsl = ((o >> 4) & 7) ^ (row & 7);   // inverse-swizzled source chunk
      gload_lds16(qkv + kgbase + (size_t)(k0 + row)*3072 + lsl*8, (char*)sK[buf] + o);
      gload_lds16(vt  + vgbase + (size_t)row*2048 + k0   + lsl*8, (char*)sV[buf] + o);
    }
  };

  for (int pass = 0; pass < 2; ++pass){
    const int qt = pass ? 31 - pairi : pairi;
    const int q0 = qt * 64;
    const int qbase = q0 + w * 16;

    // Q fragments (held in regs for the whole k-loop)
    s16x8 aq[2];
    #pragma unroll
    for (int kc = 0; kc < 2; ++kc)
      aq[kc] = *(const s16x8*)(qkv + (size_t)(b*2048 + qbase + lrow)*3072 + h*64 + kc*32 + lk*8);

    f32x4 oacc[4] = {};
    float mrun[4], lrun[4];
    #pragma unroll
    for (int r = 0; r < 4; ++r){ mrun[r] = -1e30f; lrun[r] = 0.0f; }

    const int nt = qt + 1;
    __syncthreads();                    // prior pass's reads complete
    stage(0, 0);                        // prologue
    __syncthreads();
    int cur = 0;

    for (int ktile = 0; ktile < nt; ++ktile){
      const int k0 = ktile * 64;
      if (ktile + 1 < nt) stage(cur ^ 1, k0 + 64);   // prefetch next tile

      // S = Q K^T  (per wave: 16q x 64k), K from LDS
      f32x4 sacc[4] = {};
      #pragma unroll
      for (int kc = 0; kc < 2; ++kc){
        #pragma unroll
        for (int ct = 0; ct < 4; ++ct){
          int row = ct*16 + lrow;
          int slot = (kc*4 + lk) ^ (row & 7);
          s16x8 bk = *(const s16x8*)&sK[cur][row*64 + slot*8];
          sacc[ct] = __builtin_amdgcn_mfma_f32_16x16x32_bf16(aq[kc], bk, sacc[ct], 0, 0, 0);
        }
      }

      float s[4][4];
      const bool need_mask = (k0 + 63 > qbase);
      #pragma unroll
      for (int ct = 0; ct < 4; ++ct){
        #pragma unroll
        for (int r = 0; r < 4; ++r){
          float v = sacc[ct][r] * 0.125f;               // 1/sqrt(64)
          if (need_mask){
            int qi = qbase + lk*4 + r;
            int ki = k0 + ct*16 + lrow;
            if (ki > qi) v = -10000.0f;                 // reference's mask value
          }
          s[ct][r] = v;
        }
      }

      // online softmax per q-row (row spread over 16 lanes sharing lk)
      #pragma unroll
      for (int r = 0; r < 4; ++r){
        float mx = fmaxf(fmaxf(s[0][r], s[1][r]), fmaxf(s[2][r], s[3][r]));
        #pragma unroll
        for (int off = 1; off < 16; off <<= 1)
          mx = fmaxf(mx, __shfl_xor(mx, off, 64));
        float mnew = fmaxf(mrun[r], mx);
        float sf = __expf(mrun[r] - mnew);
        lrun[r] *= sf;
        #pragma unroll
        for (int dt = 0; dt < 4; ++dt) oacc[dt][r] *= sf;
        float ts = 0.0f;
        #pragma unroll
        for (int ct = 0; ct < 4; ++ct){
          float p = __expf(s[ct][r] - mnew);
          s[ct][r] = p;
          ts += p;
        }
        #pragma unroll
        for (int off = 1; off < 16; off <<= 1)
          ts += __shfl_xor(ts, off, 64);
        lrun[r] += ts;
        mrun[r] = mnew;
      }

      // P -> LDS (bf16), wave-private
      #pragma unroll
      for (int ct = 0; ct < 4; ++ct)
        #pragma unroll
        for (int r = 0; r < 4; ++r)
          sP[w][lk*4 + r][ct*16 + lrow] = f2bf(s[ct][r]);

      // O += P V   (A = P[16q][64k], B^T = V^T[d][k] from LDS)
      s16x8 pa[2];
      #pragma unroll
      for (int kc = 0; kc < 2; ++kc)
        pa[kc] = *(const s16x8*)&sP[w][lrow][kc*32 + lk*8];
      #pragma unroll
      for (int dt = 0; dt < 4; ++dt){
        #pragma unroll
        for (int kc = 0; kc < 2; ++kc){
          int row = dt*16 + lrow;
          int slot = (kc*4 + lk) ^ (row & 7);
          s16x8 bv = *(const s16x8*)&sV[cur][row*64 + slot*8];
          oacc[dt] = __builtin_amdgcn_mfma_f32_16x16x32_bf16(pa[kc], bv, oacc[dt], 0, 0, 0);
        }
      }

      __syncthreads();                  // all waves done with `cur`; prefetch drained
      cur ^= 1;
    }

    #pragma unroll
    for (int r = 0; r < 4; ++r){
      float inv = 1.0f / lrun[r];
      int row = b*2048 + qbase + lk*4 + r;
      #pragma unroll
      for (int dt = 0; dt < 4; ++dt){
        int col = h*64 + dt*16 + lrow;
        ob[(size_t)row * 1024 + col] = f2bf(oacc[dt][r] * inv);
      }
    }
  }
}

// ---------------- LayerNorm over D=1024, one block per row -----------------
__global__ __launch_bounds__(256) void ln_kernel(
    const float* __restrict__ in, const float* __restrict__ g,
    const float* __restrict__ b, void* __restrict__ out, int bf16_out)
{
  const int row = blockIdx.x;
  const int t = threadIdx.x;
  float4 v = *(const float4*)(in + (size_t)row*1024 + t*4);
  float s = v.x + v.y + v.z + v.w;
  float q = v.x*v.x + v.y*v.y + v.z*v.z + v.w*v.w;
  #pragma unroll
  for (int off = 1; off < 64; off <<= 1){
    s += __shfl_xor(s, off, 64);
    q += __shfl_xor(q, off, 64);
  }
  __shared__ float ss[4], sq[4];
  if ((t & 63) == 0){ ss[t >> 6] = s; sq[t >> 6] = q; }
  __syncthreads();
  s = ss[0] + ss[1] + ss[2] + ss[3];
  q = sq[0] + sq[1] + sq[2] + sq[3];
  float mu = s * (1.0f/1024.0f);
  float var = q * (1.0f/1024.0f) - mu*mu;
  float rs = rsqrtf(var + 1e-5f);
  float4 gg = *(const float4*)(g + t*4);
  float4 bb = *(const float4*)(b + t*4);
  float o0 = (v.x - mu)*rs*gg.x + bb.x;
  float o1 = (v.y - mu)*rs*gg.y + bb.y;
  float o2 = (v.z - mu)*rs*gg.z + bb.z;
  float o3 = (v.w - mu)*rs*gg.w + bb.w;
  if (bf16_out){
    short4 o; o.x = f2bf(o0); o.y = f2bf(o1); o.z = f2bf(o2); o.w = f2bf(o3);
    *(short4*)((short*)out + (size_t)row*1024 + t*4) = o;
  } else {
    float4 o = {o0, o1, o2, o3};
    *(float4*)((float*)out + (size_t)row*1024 + t*4) = o;
  }
}

// -------- LN2 fused with split-K reduce: LN(p0 + p1 + bias + bf16 resid) ---
__global__ __launch_bounds__(256) void ln_fused2(
    const float* __restrict__ p0, const float* __restrict__ p1,
    const float* __restrict__ bias, const short* __restrict__ resid,
    const float* __restrict__ g, const float* __restrict__ b,
    float* __restrict__ out)
{
  const int row = blockIdx.x;
  const int t = threadIdx.x;
  const size_t base = (size_t)row*1024 + t*4;
  float4 a0 = *(const float4*)(p0 + base);
  float4 a1 = *(const float4*)(p1 + base);
  float4 bi = *(const float4*)(bias + t*4);
  short4 rr = *(const short4*)(resid + base);
  float v0 = a0.x + a1.x + bi.x + bf2f(rr.x);
  float v1 = a0.y + a1.y + bi.y + bf2f(rr.y);
  float v2 = a0.z + a1.z + bi.z + bf2f(rr.z);
  float v3 = a0.w + a1.w + bi.w + bf2f(rr.w);
  float s = v0 + v1 + v2 + v3;
  float q = v0*v0 + v1*v1 + v2*v2 + v3*v3;
  #pragma unroll
  for (int off = 1; off < 64; off <<= 1){
    s += __shfl_xor(s, off, 64);
    q += __shfl_xor(q, off, 64);
  }
  __shared__ float ss[4], sq[4];
  if ((t & 63) == 0){ ss[t >> 6] = s; sq[t >> 6] = q; }
  __syncthreads();
  s = ss[0] + ss[1] + ss[2] + ss[3];
  q = sq[0] + sq[1] + sq[2] + sq[3];
  float mu = s * (1.0f/1024.0f);
  float var = q * (1.0f/1024.0f) - mu*mu;
  float rs = rsqrtf(var + 1e-5f);
  float4 gg = *(const float4*)(g + t*4);
  float4 bb = *(const float4*)(b + t*4);
  float4 o;
  o.x = (v0 - mu)*rs*gg.x + bb.x;
  o.y = (v1 - mu)*rs*gg.y + bb.y;
  o.z = (v2 - mu)*rs*gg.z + bb.z;
  o.w = (v3 - mu)*rs*gg.w + bb.w;
  *(float4*)(out + base) = o;
}

// ---------------------------------------------------------------------------
extern "C" void kernel_launch(void* const* d_in, const int* in_sizes, int n_in,
                              void* d_out, int out_size, void* d_ws, size_t ws_size,
                              hipStream_t stream) {
  const float* x      = (const float*)d_in[0];
  const float* w_attn = (const float*)d_in[1];
  const float* b_attn = (const float*)d_in[2];
  const float* w_o    = (const float*)d_in[3];
  const float* b_o    = (const float*)d_in[4];
  const float* ln1_g  = (const float*)d_in[5];
  const float* ln1_b  = (const float*)d_in[6];
  const float* w_fc   = (const float*)d_in[7];
  const float* b_fc   = (const float*)d_in[8];
  const float* w_pr   = (const float*)d_in[9];
  const float* b_pr   = (const float*)d_in[10];
  const float* ln2_g  = (const float*)d_in[11];
  const float* ln2_b  = (const float*)d_in[12];

  char* ws = (char*)d_ws;
  // workspace layout (aliased where lifetimes permit) — high-water ~97 MB
  short* xb   = (short*)(ws + 0);          // 8 MB  [4096][1024] bf16 (steps 1-6)
  short* vt   = (short*)(ws + 0);          // 8 MB  (steps 7-8, aliases xb)
  float* pp0  = (float*)(ws + 0);          // 16.8 MB split-K partial 0 (steps 12-13)
  short* waT  = (short*)(ws + 8388608);    // 6 MB  [3072][1024] (steps 2-6)
  short* woT  = (short*)(ws + 14680064);   // 2 MB  [1024][1024] (steps 2-9)
  short* wfT  = (short*)(ws + 16777216);   // 8 MB  [4096][1024] (steps 2-11)
  short* wpT  = (short*)(ws + 25165824);   // 8 MB  [1024][4096] (steps 2-12)
  short* qkvb = (short*)(ws + 33554432);   // 24 MB [4096][3072] (steps 6-8)
  short* fb   = (short*)(ws + 33554432);   // 32 MB [4096][4096] (steps 11-12, aliases qkvb)
  short* ob   = (short*)(ws + 67108864);   // 8 MB  [4096][1024] (steps 8-9)
  float* pp1  = (float*)(ws + 67108864);   // 16.8 MB split-K partial 1 (steps 12-13, aliases ob/r1)
  float* r1   = (float*)(ws + 75497472);   // 16.8 MB [4096][1024] f32 (steps 9-10)
  short* nb   = (short*)(ws + 92274688);   // 8 MB  [4096][1024] (steps 10-13)

  const int M = 4096;

  // 1. x -> bf16
  cvt_f32_bf16<<<dim3(M*1024/1024), dim3(256), 0, stream>>>(x, xb, M*1024);
  // 2-5. weight transposes (f32 [K][N] -> bf16 [N][K])
  wtrans<<<dim3(3072/32, 1024/32), dim3(32,8), 0, stream>>>(w_attn, waT, 1024, 3072);
  wtrans<<<dim3(1024/32, 1024/32), dim3(32,8), 0, stream>>>(w_o,   woT, 1024, 1024);
  wtrans<<<dim3(4096/32, 1024/32), dim3(32,8), 0, stream>>>(w_fc,  wfT, 1024, 4096);
  wtrans<<<dim3(1024/32, 4096/32), dim3(32,8), 0, stream>>>(w_pr,  wpT, 4096, 1024);
  // 6. qkv = x @ w_attn + b_attn  (bf16 out)
  gemm_bf16<<<dim3(3072/GBN, M/GBM), dim3(256), 0, stream>>>(
      xb, waT, b_attn, nullptr, qkvb, nullptr, M, 3072, 1024, 0, 1);
  // 7. vt = transpose of V per (b,h)
  vtrans<<<dim3(2048/32, 64/32, 32), dim3(32,8), 0, stream>>>(qkvb, vt);
  // 8. attention -> ob (bf16)
  attn_kernel<<<dim3(16, 16, 2), dim3(256), 0, stream>>>(qkvb, vt, ob);
  // 9. r1 = x + (o @ w_o + b_o)   (f32 out)
  gemm_bf16<<<dim3(1024/GBN, M/GBM), dim3(256), 0, stream>>>(
      ob, woT, b_o, x, r1, nullptr, M, 1024, 1024, 1, 1);
  // 10. n = LN(r1) -> nb (bf16)
  ln_kernel<<<dim3(M), dim3(256), 0, stream>>>(r1, ln1_g, ln1_b, nb, 1);
  // 11. f = gelu(n @ w_fc + b_fc) -> fb (bf16)
  gemm_bf16<<<dim3(4096/GBN, M/GBM), dim3(256), 0, stream>>>(
      nb, wfT, b_fc, nullptr, fb, nullptr, M, 4096, 1024, 2, 1);
  // 12. split-K=2: pp0/pp1 = fb @ w_pr partials (raw f32)
  gemm_bf16<<<dim3(1024/GBN, M/GBM, 2), dim3(256), 0, stream>>>(
      fb, wpT, nullptr, nullptr, pp0, pp1, M, 1024, 4096, 4, 2);
  // 13. h = LN(pp0 + pp1 + b_pr + nb) -> d_out (f32)
  ln_fused2<<<dim3(M), dim3(256), 0, stream>>>(pp0, pp1, b_pr, nb, ln2_g, ln2_b, (float*)d_out);
}

// Round 4
// 311.964 us; speedup vs baseline: 1.5284x; 1.0021x over previous
//
#include <hip/hip_runtime.h>
#include <stdint.h>
#include <math.h>

// ---------------------------------------------------------------------------
// Transformer block (B=2, S=2048, D=1024, H=16, hd=64, F=4096), post-LN.
// bf16 MFMA for all matmuls, fp32 accumulate. Threshold is 2% of |ref|max.
// ---------------------------------------------------------------------------

typedef __attribute__((ext_vector_type(4))) float f32x4;
typedef __attribute__((ext_vector_type(8))) short s16x8;

__device__ __forceinline__ float bf2f(short s){
  unsigned u = ((unsigned)(unsigned short)s) << 16;
  return __builtin_bit_cast(float, u);
}
__device__ __forceinline__ short f2bf(float f){
  unsigned u = __builtin_bit_cast(unsigned, f);
  unsigned r = (u + 0x7fffu + ((u >> 16) & 1u)) >> 16;   // RNE
  return (short)(unsigned short)r;
}

__device__ __forceinline__ void gload_lds16(const void* gp, void* lp){
  __builtin_amdgcn_global_load_lds(
      (__attribute__((address_space(1))) void*)const_cast<void*>(gp),
      (__attribute__((address_space(3))) void*)lp,
      16, 0, 0);
}

// ---------------- elementwise f32 -> bf16 ----------------------------------
__global__ void cvt_f32_bf16(const float* __restrict__ in, short* __restrict__ out, int n){
  int i = (blockIdx.x * blockDim.x + threadIdx.x) * 4;
  if (i < n){
    float4 v = *(const float4*)(in + i);
    short4 o;
    o.x = f2bf(v.x); o.y = f2bf(v.y); o.z = f2bf(v.z); o.w = f2bf(v.w);
    *(short4*)(out + i) = o;
  }
}

// ---------------- weight transpose+convert: in[R][C] f32 -> out[C][R] bf16 --
__global__ __launch_bounds__(256) void wtrans(const float* __restrict__ in,
                                              short* __restrict__ out, int R, int C){
  __shared__ float tile[32][33];
  int c0 = blockIdx.x * 32, r0 = blockIdx.y * 32;
  int tx = threadIdx.x, ty = threadIdx.y;        // block (32,8)
  #pragma unroll
  for (int j = 0; j < 4; ++j)
    tile[ty + j*8][tx] = in[(size_t)(r0 + ty + j*8) * C + c0 + tx];
  __syncthreads();
  #pragma unroll
  for (int j = 0; j < 4; ++j)
    out[(size_t)(c0 + ty + j*8) * R + r0 + tx] = f2bf(tile[tx][ty + j*8]);
}

// ---------------- V transpose: qkv[b*2048+s][2048+h*64+d] -> vt[(bh*64+d)][s]
__global__ __launch_bounds__(256) void vtrans(const short* __restrict__ qkv,
                                              short* __restrict__ vt){
  __shared__ short tile[32][33];
  int bh = blockIdx.z; int b = bh >> 4, h = bh & 15;
  int s0 = blockIdx.x * 32, d0 = blockIdx.y * 32;
  int tx = threadIdx.x, ty = threadIdx.y;
  #pragma unroll
  for (int j = 0; j < 4; ++j)
    tile[ty + j*8][tx] = qkv[(size_t)(b*2048 + s0 + ty + j*8) * 3072 + 2048 + h*64 + d0 + tx];
  __syncthreads();
  #pragma unroll
  for (int j = 0; j < 4; ++j)
    vt[(size_t)(bh*64 + d0 + ty + j*8) * 2048 + s0 + tx] = tile[tx][ty + j*8];
}

// ---------------- GEMM: C[M][N] = A[M][K](bf16) @ BT[N][K](bf16)^T ---------
// EPI: 0 = store bf16 (acc + bias)                              (qkv)
//      1 = store f32 (acc + bias + aux_f32[row*N+col])          (r1 = x + attn)
//      2 = gelu exact on acc + bias, store bf16                 (fc)
//      4 = raw bf16 partial to outz[blockIdx.z]                 (split-K)
#define GBM 128
#define GBN 128
#define GBK 64

__global__ __launch_bounds__(256, 2) void gemm_bf16(
    const short* __restrict__ A, const short* __restrict__ BT,
    const float* __restrict__ bias, const float* __restrict__ aux_f32,
    void* __restrict__ out, void* __restrict__ out2,
    void* __restrict__ out3, void* __restrict__ out4,
    int M, int N, int K, int EPI, int KS)
{
  __shared__ short sA[GBM * GBK];   // 16 KB, rows of 64 shorts (128 B), XOR-swizzled slots
  __shared__ short sB[GBN * GBK];   // 16 KB
  const int t = threadIdx.x;
  const int lane = t & 63;
  const int w = t >> 6;
  const int wr = w >> 1, wc = w & 1;            // 2x2 wave grid, each wave 64x64
  const int m0 = blockIdx.y * GBM, n0 = blockIdx.x * GBN;
  const int lrow = lane & 15;
  const int lk = lane >> 4;

  const int Kspl = K / KS;
  const int kbeg = blockIdx.z * Kspl;

  f32x4 acc[4][4] = {};

  for (int kk = kbeg; kk < kbeg + Kspl; kk += GBK){
    __syncthreads();                            // prior reads done before overwrite
    #pragma unroll
    for (int r = 0; r < 4; ++r){                // stage A: 4 rounds x 4 KB
      int o = r * 4096 + t * 16;                // linear LDS byte offset
      int row = o >> 7;                         // 128 B per row
      int phys = (o >> 4) & 7;                  // 16B slot within row
      int lsl = phys ^ (row & 7);               // inverse-swizzled source chunk
      gload_lds16(A + (size_t)(m0 + row) * K + kk + lsl * 8, (char*)sA + o);
    }
    #pragma unroll
    for (int r = 0; r < 4; ++r){                // stage BT
      int o = r * 4096 + t * 16;
      int row = o >> 7;
      int phys = (o >> 4) & 7;
      int lsl = phys ^ (row & 7);
      gload_lds16(BT + (size_t)(n0 + row) * K + kk + lsl * 8, (char*)sB + o);
    }
    __syncthreads();                            // drains vmcnt before barrier

    #pragma unroll
    for (int kc = 0; kc < 2; ++kc){
      s16x8 af[4], bf[4];
      #pragma unroll
      for (int rt = 0; rt < 4; ++rt){
        int row = wr*64 + rt*16 + lrow;
        int slot = (kc*4 + lk) ^ (row & 7);     // swizzled read
        af[rt] = *(const s16x8*)&sA[row*64 + slot*8];
      }
      #pragma unroll
      for (int ct = 0; ct < 4; ++ct){
        int row = wc*64 + ct*16 + lrow;
        int slot = (kc*4 + lk) ^ (row & 7);
        bf[ct] = *(const s16x8*)&sB[row*64 + slot*8];
      }
      #pragma unroll
      for (int rt = 0; rt < 4; ++rt)
        #pragma unroll
        for (int ct = 0; ct < 4; ++ct)
          acc[rt][ct] = __builtin_amdgcn_mfma_f32_16x16x32_bf16(af[rt], bf[ct], acc[rt][ct], 0, 0, 0);
    }
  }

  void* pz = (blockIdx.z == 0) ? out : (blockIdx.z == 1) ? out2
           : (blockIdx.z == 2) ? out3 : out4;
  #pragma unroll
  for (int rt = 0; rt < 4; ++rt){
    #pragma unroll
    for (int ct = 0; ct < 4; ++ct){
      #pragma unroll
      for (int r = 0; r < 4; ++r){
        int row = m0 + wr*64 + rt*16 + lk*4 + r;    // C/D: row=(lane>>4)*4+reg
        int col = n0 + wc*64 + ct*16 + lrow;        //      col=lane&15
        size_t idx = (size_t)row * N + col;
        if (EPI == 4){
          ((short*)pz)[idx] = f2bf(acc[rt][ct][r]);
        } else {
          float v = acc[rt][ct][r] + bias[col];
          if (EPI == 0){
            ((short*)out)[idx] = f2bf(v);
          } else if (EPI == 1){
            ((float*)out)[idx] = v + aux_f32[idx];
          } else {
            float g = 0.5f * v * (1.0f + erff(v * 0.70710678118654752f));
            ((short*)out)[idx] = f2bf(g);
          }
        }
      }
    }
  }
}

// ---------------- flash attention (causal), LDS-staged K/V, paired q-tiles --
// 512 blocks, 1-D grid, decoded so all 16 q-tile blocks of one (b,h) land on
// the same XCD (P%8 constant) -> K/V stay resident in that XCD's L2.
// Block = 4 waves; wave w owns q-rows [qt*64 + w*16, +16). Each block handles
// q-tile `pairi` then `31-pairi` -> every block does exactly 33 k-tiles.
__global__ __launch_bounds__(256, 2) void attn_kernel(
    const short* __restrict__ qkv, const short* __restrict__ vt,
    short* __restrict__ ob)
{
  const int P = blockIdx.x;
  const int xcd = P & 7;
  const int idx = P >> 3;
  const int pairi = idx & 15;           // 0..15
  const int bh = xcd + ((idx >> 4) << 3);
  const int b = bh >> 4, h = bh & 15;
  const int t  = threadIdx.x;
  const int lane = t & 63;
  const int w = t >> 6;
  const int lrow = lane & 15, lk = lane >> 4;

  __shared__ short sK[2][64*64];        // 2 x 8 KB, rows of 64 shorts, XOR-swizzled
  __shared__ short sV[2][64*64];        // 2 x 8 KB
  __shared__ short sP[4][16][68];       // per-wave P tile, +4 shorts pad

  const size_t kgbase = (size_t)(b*2048)*3072 + 1024 + h*64;   // K rows in qkv
  const size_t vgbase = (size_t)((b*16 + h)*64)*2048;          // V^T rows in vt

  auto stage = [&](int buf, int k0){
    #pragma unroll
    for (int r2 = 0; r2 < 2; ++r2){     // 8 KB per tile: 2 rounds x 4 KB
      int o = r2*4096 + t*16;           // linear LDS byte offset
      int row = o >> 7;                 // 128 B per row
      int lsl = ((o >> 4) & 7) ^ (row & 7);   // inverse-swizzled source chunk
      gload_lds16(qkv + kgbase + (size_t)(k0 + row)*3072 + lsl*8, (char*)sK[buf] + o);
      gload_lds16(vt  + vgbase + (size_t)row*2048 + k0   + lsl*8, (char*)sV[buf] + o);
    }
  };

  for (int pass = 0; pass < 2; ++pass){
    const int qt = pass ? 31 - pairi : pairi;
    const int q0 = qt * 64;
    const int qbase = q0 + w * 16;

    // Q fragments (held in regs for the whole k-loop)
    s16x8 aq[2];
    #pragma unroll
    for (int kc = 0; kc < 2; ++kc)
      aq[kc] = *(const s16x8*)(qkv + (size_t)(b*2048 + qbase + lrow)*3072 + h*64 + kc*32 + lk*8);

    f32x4 oacc[4] = {};
    float mrun[4], lrun[4];
    #pragma unroll
    for (int r = 0; r < 4; ++r){ mrun[r] = -1e30f; lrun[r] = 0.0f; }

    const int nt = qt + 1;
    __syncthreads();                    // prior pass's reads complete
    stage(0, 0);                        // prologue
    __syncthreads();
    int cur = 0;

    for (int ktile = 0; ktile < nt; ++ktile){
      const int k0 = ktile * 64;
      if (ktile + 1 < nt) stage(cur ^ 1, k0 + 64);   // prefetch next tile

      // S = Q K^T  (per wave: 16q x 64k), K from LDS
      f32x4 sacc[4] = {};
      __builtin_amdgcn_s_setprio(1);
      #pragma unroll
      for (int kc = 0; kc < 2; ++kc){
        #pragma unroll
        for (int ct = 0; ct < 4; ++ct){
          int row = ct*16 + lrow;
          int slot = (kc*4 + lk) ^ (row & 7);
          s16x8 bk = *(const s16x8*)&sK[cur][row*64 + slot*8];
          sacc[ct] = __builtin_amdgcn_mfma_f32_16x16x32_bf16(aq[kc], bk, sacc[ct], 0, 0, 0);
        }
      }
      __builtin_amdgcn_s_setprio(0);

      float s[4][4];
      const bool need_mask = (k0 + 63 > qbase);
      #pragma unroll
      for (int ct = 0; ct < 4; ++ct){
        #pragma unroll
        for (int r = 0; r < 4; ++r){
          float v = sacc[ct][r] * 0.125f;               // 1/sqrt(64)
          if (need_mask){
            int qi = qbase + lk*4 + r;
            int ki = k0 + ct*16 + lrow;
            if (ki > qi) v = -10000.0f;                 // reference's mask value
          }
          s[ct][r] = v;
        }
      }

      // online softmax per q-row (row spread over 16 lanes sharing lk)
      #pragma unroll
      for (int r = 0; r < 4; ++r){
        float mx = fmaxf(fmaxf(s[0][r], s[1][r]), fmaxf(s[2][r], s[3][r]));
        #pragma unroll
        for (int off = 1; off < 16; off <<= 1)
          mx = fmaxf(mx, __shfl_xor(mx, off, 64));
        float mnew = fmaxf(mrun[r], mx);
        float sf = __expf(mrun[r] - mnew);
        lrun[r] *= sf;
        #pragma unroll
        for (int dt = 0; dt < 4; ++dt) oacc[dt][r] *= sf;
        float ts = 0.0f;
        #pragma unroll
        for (int ct = 0; ct < 4; ++ct){
          float p = __expf(s[ct][r] - mnew);
          s[ct][r] = p;
          ts += p;
        }
        #pragma unroll
        for (int off = 1; off < 16; off <<= 1)
          ts += __shfl_xor(ts, off, 64);
        lrun[r] += ts;
        mrun[r] = mnew;
      }

      // P -> LDS (bf16), wave-private
      #pragma unroll
      for (int ct = 0; ct < 4; ++ct)
        #pragma unroll
        for (int r = 0; r < 4; ++r)
          sP[w][lk*4 + r][ct*16 + lrow] = f2bf(s[ct][r]);

      // O += P V   (A = P[16q][64k], B^T = V^T[d][k] from LDS)
      s16x8 pa[2];
      #pragma unroll
      for (int kc = 0; kc < 2; ++kc)
        pa[kc] = *(const s16x8*)&sP[w][lrow][kc*32 + lk*8];
      __builtin_amdgcn_s_setprio(1);
      #pragma unroll
      for (int dt = 0; dt < 4; ++dt){
        #pragma unroll
        for (int kc = 0; kc < 2; ++kc){
          int row = dt*16 + lrow;
          int slot = (kc*4 + lk) ^ (row & 7);
          s16x8 bv = *(const s16x8*)&sV[cur][row*64 + slot*8];
          oacc[dt] = __builtin_amdgcn_mfma_f32_16x16x32_bf16(pa[kc], bv, oacc[dt], 0, 0, 0);
        }
      }
      __builtin_amdgcn_s_setprio(0);

      __syncthreads();                  // all waves done with `cur`; prefetch drained
      cur ^= 1;
    }

    #pragma unroll
    for (int r = 0; r < 4; ++r){
      float inv = 1.0f / lrun[r];
      int row = b*2048 + qbase + lk*4 + r;
      #pragma unroll
      for (int dt = 0; dt < 4; ++dt){
        int col = h*64 + dt*16 + lrow;
        ob[(size_t)row * 1024 + col] = f2bf(oacc[dt][r] * inv);
      }
    }
  }
}

// ---------------- LayerNorm over D=1024, one block per row -----------------
__global__ __launch_bounds__(256) void ln_kernel(
    const float* __restrict__ in, const float* __restrict__ g,
    const float* __restrict__ b, void* __restrict__ out, int bf16_out)
{
  const int row = blockIdx.x;
  const int t = threadIdx.x;
  float4 v = *(const float4*)(in + (size_t)row*1024 + t*4);
  float s = v.x + v.y + v.z + v.w;
  float q = v.x*v.x + v.y*v.y + v.z*v.z + v.w*v.w;
  #pragma unroll
  for (int off = 1; off < 64; off <<= 1){
    s += __shfl_xor(s, off, 64);
    q += __shfl_xor(q, off, 64);
  }
  __shared__ float ss[4], sq[4];
  if ((t & 63) == 0){ ss[t >> 6] = s; sq[t >> 6] = q; }
  __syncthreads();
  s = ss[0] + ss[1] + ss[2] + ss[3];
  q = sq[0] + sq[1] + sq[2] + sq[3];
  float mu = s * (1.0f/1024.0f);
  float var = q * (1.0f/1024.0f) - mu*mu;
  float rs = rsqrtf(var + 1e-5f);
  float4 gg = *(const float4*)(g + t*4);
  float4 bb = *(const float4*)(b + t*4);
  float o0 = (v.x - mu)*rs*gg.x + bb.x;
  float o1 = (v.y - mu)*rs*gg.y + bb.y;
  float o2 = (v.z - mu)*rs*gg.z + bb.z;
  float o3 = (v.w - mu)*rs*gg.w + bb.w;
  if (bf16_out){
    short4 o; o.x = f2bf(o0); o.y = f2bf(o1); o.z = f2bf(o2); o.w = f2bf(o3);
    *(short4*)((short*)out + (size_t)row*1024 + t*4) = o;
  } else {
    float4 o = {o0, o1, o2, o3};
    *(float4*)((float*)out + (size_t)row*1024 + t*4) = o;
  }
}

// -------- LN2 fused with split-K4 reduce: LN(p0+p1+p2+p3 + bias + resid) ---
__global__ __launch_bounds__(256) void ln_fused4(
    const short* __restrict__ p0, const short* __restrict__ p1,
    const short* __restrict__ p2, const short* __restrict__ p3,
    const float* __restrict__ bias, const short* __restrict__ resid,
    const float* __restrict__ g, const float* __restrict__ b,
    float* __restrict__ out)
{
  const int row = blockIdx.x;
  const int t = threadIdx.x;
  const size_t base = (size_t)row*1024 + t*4;
  short4 a0 = *(const short4*)(p0 + base);
  short4 a1 = *(const short4*)(p1 + base);
  short4 a2 = *(const short4*)(p2 + base);
  short4 a3 = *(const short4*)(p3 + base);
  float4 bi = *(const float4*)(bias + t*4);
  short4 rr = *(const short4*)(resid + base);
  float v0 = bf2f(a0.x) + bf2f(a1.x) + bf2f(a2.x) + bf2f(a3.x) + bi.x + bf2f(rr.x);
  float v1 = bf2f(a0.y) + bf2f(a1.y) + bf2f(a2.y) + bf2f(a3.y) + bi.y + bf2f(rr.y);
  float v2 = bf2f(a0.z) + bf2f(a1.z) + bf2f(a2.z) + bf2f(a3.z) + bi.z + bf2f(rr.z);
  float v3 = bf2f(a0.w) + bf2f(a1.w) + bf2f(a2.w) + bf2f(a3.w) + bi.w + bf2f(rr.w);
  float s = v0 + v1 + v2 + v3;
  float q = v0*v0 + v1*v1 + v2*v2 + v3*v3;
  #pragma unroll
  for (int off = 1; off < 64; off <<= 1){
    s += __shfl_xor(s, off, 64);
    q += __shfl_xor(q, off, 64);
  }
  __shared__ float ss[4], sq[4];
  if ((t & 63) == 0){ ss[t >> 6] = s; sq[t >> 6] = q; }
  __syncthreads();
  s = ss[0] + ss[1] + ss[2] + ss[3];
  q = sq[0] + sq[1] + sq[2] + sq[3];
  float mu = s * (1.0f/1024.0f);
  float var = q * (1.0f/1024.0f) - mu*mu;
  float rs = rsqrtf(var + 1e-5f);
  float4 gg = *(const float4*)(g + t*4);
  float4 bb = *(const float4*)(b + t*4);
  float4 o;
  o.x = (v0 - mu)*rs*gg.x + bb.x;
  o.y = (v1 - mu)*rs*gg.y + bb.y;
  o.z = (v2 - mu)*rs*gg.z + bb.z;
  o.w = (v3 - mu)*rs*gg.w + bb.w;
  *(float4*)(out + base) = o;
}

// ---------------------------------------------------------------------------
extern "C" void kernel_launch(void* const* d_in, const int* in_sizes, int n_in,
                              void* d_out, int out_size, void* d_ws, size_t ws_size,
                              hipStream_t stream) {
  const float* x      = (const float*)d_in[0];
  const float* w_attn = (const float*)d_in[1];
  const float* b_attn = (const float*)d_in[2];
  const float* w_o    = (const float*)d_in[3];
  const float* b_o    = (const float*)d_in[4];
  const float* ln1_g  = (const float*)d_in[5];
  const float* ln1_b  = (const float*)d_in[6];
  const float* w_fc   = (const float*)d_in[7];
  const float* b_fc   = (const float*)d_in[8];
  const float* w_pr   = (const float*)d_in[9];
  const float* b_pr   = (const float*)d_in[10];
  const float* ln2_g  = (const float*)d_in[11];
  const float* ln2_b  = (const float*)d_in[12];

  char* ws = (char*)d_ws;
  const size_t MB = 1048576;
  // workspace layout (aliased by lifetime) — high-water 88 MiB
  short* waT  = (short*)(ws + 0);          // 6 MiB  [3072][1024]  (steps 2-6)
  short* woT  = (short*)(ws + 6*MB);       // 2 MiB  [1024][1024]  (steps 2-9)
  short* wfT  = (short*)(ws + 8*MB);       // 8 MiB  [4096][1024]  (steps 2-11)
  short* wpT  = (short*)(ws + 16*MB);      // 8 MiB  [1024][4096]  (steps 2-12)
  short* xb   = (short*)(ws + 24*MB);      // 8 MiB  [4096][1024]  (steps 1-6)
  short* vt   = (short*)(ws + 24*MB);      // 8 MiB  (steps 7-8, aliases xb)
  short* qkvb = (short*)(ws + 32*MB);      // 24 MiB [4096][3072]  (steps 6-8)
  short* fb   = (short*)(ws + 32*MB);      // 32 MiB [4096][4096]  (steps 11-12, aliases qkvb+ob)
  short* ob   = (short*)(ws + 56*MB);      // 8 MiB  [4096][1024]  (steps 8-9)
  float* r1   = (float*)(ws + 64*MB);      // 16 MiB [4096][1024]  (steps 9-10)
  short* pp0  = (short*)(ws + 64*MB);      // 8 MiB  bf16 partial  (steps 12-13, aliases r1)
  short* pp1  = (short*)(ws + 72*MB);      // 8 MiB
  short* pp2  = (short*)(ws + 0);          // 8 MiB  (aliases waT/woT, dead by 12)
  short* pp3  = (short*)(ws + 8*MB);       // 8 MiB  (aliases wfT, dead by 12)
  short* nb   = (short*)(ws + 80*MB);      // 8 MiB  [4096][1024]  (steps 10-13)

  const int M = 4096;

  // 1. x -> bf16
  cvt_f32_bf16<<<dim3(M*1024/1024), dim3(256), 0, stream>>>(x, xb, M*1024);
  // 2-5. weight transposes (f32 [K][N] -> bf16 [N][K])
  wtrans<<<dim3(3072/32, 1024/32), dim3(32,8), 0, stream>>>(w_attn, waT, 1024, 3072);
  wtrans<<<dim3(1024/32, 1024/32), dim3(32,8), 0, stream>>>(w_o,   woT, 1024, 1024);
  wtrans<<<dim3(4096/32, 1024/32), dim3(32,8), 0, stream>>>(w_fc,  wfT, 1024, 4096);
  wtrans<<<dim3(1024/32, 4096/32), dim3(32,8), 0, stream>>>(w_pr,  wpT, 4096, 1024);
  // 6. qkv = x @ w_attn + b_attn  (bf16 out)
  gemm_bf16<<<dim3(3072/GBN, M/GBM), dim3(256), 0, stream>>>(
      xb, waT, b_attn, nullptr, qkvb, nullptr, nullptr, nullptr, M, 3072, 1024, 0, 1);
  // 7. vt = transpose of V per (b,h)
  vtrans<<<dim3(2048/32, 64/32, 32), dim3(32,8), 0, stream>>>(qkvb, vt);
  // 8. attention -> ob (bf16); 512 blocks, XCD-chunked decode inside
  attn_kernel<<<dim3(512), dim3(256), 0, stream>>>(qkvb, vt, ob);
  // 9. r1 = x + (o @ w_o + b_o)   (f32 out)
  gemm_bf16<<<dim3(1024/GBN, M/GBM), dim3(256), 0, stream>>>(
      ob, woT, b_o, x, r1, nullptr, nullptr, nullptr, M, 1024, 1024, 1, 1);
  // 10. n = LN(r1) -> nb (bf16)
  ln_kernel<<<dim3(M), dim3(256), 0, stream>>>(r1, ln1_g, ln1_b, nb, 1);
  // 11. f = gelu(n @ w_fc + b_fc) -> fb (bf16)
  gemm_bf16<<<dim3(4096/GBN, M/GBM), dim3(256), 0, stream>>>(
      nb, wfT, b_fc, nullptr, fb, nullptr, nullptr, nullptr, M, 4096, 1024, 2, 1);
  // 12. split-K=4: pp0..pp3 = fb @ w_pr partials (bf16)
  gemm_bf16<<<dim3(1024/GBN, M/GBM, 4), dim3(256), 0, stream>>>(
      fb, wpT, nullptr, nullptr, pp0, pp1, pp2, pp3, M, 1024, 4096, 4, 4);
  // 13. h = LN(pp0+pp1+pp2+pp3 + b_pr + nb) -> d_out (f32)
  ln_fused4<<<dim3(M), dim3(256), 0, stream>>>(pp0, pp1, pp2, pp3, b_pr, nb,
                                               ln2_g, ln2_b, (float*)d_out);
}

// Round 5
// 297.479 us; speedup vs baseline: 1.6029x; 1.0487x over previous
//
#include <hip/hip_runtime.h>
#include <stdint.h>
#include <math.h>

// ---------------------------------------------------------------------------
// Transformer block (B=2, S=2048, D=1024, H=16, hd=64, F=4096), post-LN.
// bf16 MFMA for all matmuls, fp32 accumulate. Threshold is 2% of |ref|max.
// GEMMs: 256x256 tile, BK=32, ring-4 LDS (128 KiB), counted-vmcnt pipeline.
// ---------------------------------------------------------------------------

typedef __attribute__((ext_vector_type(4))) float f32x4;
typedef __attribute__((ext_vector_type(8))) short s16x8;

__device__ __forceinline__ float bf2f(short s){
  unsigned u = ((unsigned)(unsigned short)s) << 16;
  return __builtin_bit_cast(float, u);
}
__device__ __forceinline__ short f2bf(float f){
  unsigned u = __builtin_bit_cast(unsigned, f);
  unsigned r = (u + 0x7fffu + ((u >> 16) & 1u)) >> 16;   // RNE
  return (short)(unsigned short)r;
}

__device__ __forceinline__ void gload_lds16(const void* gp, void* lp){
  __builtin_amdgcn_global_load_lds(
      (__attribute__((address_space(1))) void*)const_cast<void*>(gp),
      (__attribute__((address_space(3))) void*)lp,
      16, 0, 0);
}

// ---------------- elementwise f32 -> bf16 ----------------------------------
__global__ void cvt_f32_bf16(const float* __restrict__ in, short* __restrict__ out, int n){
  int i = (blockIdx.x * blockDim.x + threadIdx.x) * 4;
  if (i < n){
    float4 v = *(const float4*)(in + i);
    short4 o;
    o.x = f2bf(v.x); o.y = f2bf(v.y); o.z = f2bf(v.z); o.w = f2bf(v.w);
    *(short4*)(out + i) = o;
  }
}

// ---------------- weight transpose+convert: in[R][C] f32 -> out[C][R] bf16 --
__global__ __launch_bounds__(256) void wtrans(const float* __restrict__ in,
                                              short* __restrict__ out, int R, int C){
  __shared__ float tile[32][33];
  int c0 = blockIdx.x * 32, r0 = blockIdx.y * 32;
  int tx = threadIdx.x, ty = threadIdx.y;        // block (32,8)
  #pragma unroll
  for (int j = 0; j < 4; ++j)
    tile[ty + j*8][tx] = in[(size_t)(r0 + ty + j*8) * C + c0 + tx];
  __syncthreads();
  #pragma unroll
  for (int j = 0; j < 4; ++j)
    out[(size_t)(c0 + ty + j*8) * R + r0 + tx] = f2bf(tile[tx][ty + j*8]);
}

// ---------------- V transpose: qkv[b*2048+s][2048+h*64+d] -> vt[(bh*64+d)][s]
__global__ __launch_bounds__(256) void vtrans(const short* __restrict__ qkv,
                                              short* __restrict__ vt){
  __shared__ short tile[32][33];
  int bh = blockIdx.z; int b = bh >> 4, h = bh & 15;
  int s0 = blockIdx.x * 32, d0 = blockIdx.y * 32;
  int tx = threadIdx.x, ty = threadIdx.y;
  #pragma unroll
  for (int j = 0; j < 4; ++j)
    tile[ty + j*8][tx] = qkv[(size_t)(b*2048 + s0 + ty + j*8) * 3072 + 2048 + h*64 + d0 + tx];
  __syncthreads();
  #pragma unroll
  for (int j = 0; j < 4; ++j)
    vt[(size_t)(bh*64 + d0 + ty + j*8) * 2048 + s0 + tx] = tile[tx][ty + j*8];
}

// ---------------- 256x256 GEMM, BK=32, ring-4 LDS, counted vmcnt -----------
// C[M][N] = A[M][K](bf16) @ BT[N][K](bf16)^T
// EPI: 0 = bf16 (acc+bias)          (qkv)
//      2 = gelu(acc+bias) bf16      (fc)
//      4 = raw bf16 partial to o[blockIdx.z]  (split-K; bias added in LN fuse)
#define TBK 32

__global__ __launch_bounds__(512, 2) void gemm256(
    const short* __restrict__ A, const short* __restrict__ BT,
    const float* __restrict__ bias,
    void* __restrict__ o0, void* __restrict__ o1,
    void* __restrict__ o2, void* __restrict__ o3,
    int M, int N, int K, int EPI, int KS)
{
  // ring of 4 K-tiles; each slot: A 128x... = [256 rows][32k] (16KB) then B (16KB)
  __shared__ __attribute__((aligned(16))) short lds[4][16384];
  const int t = threadIdx.x;
  const int lane = t & 63;
  const int wid = t >> 6;
  const int wr = wid >> 2, wc = wid & 3;        // 2x4 wave grid, wave owns 128x64
  const int lrow = lane & 15, lk = lane >> 4;

  // bijective XCD-chunked remap of (bx,by); all grids here have nwg % 8 == 0
  const int gx = gridDim.x;
  const int nwg = gx * gridDim.y;
  const int P = blockIdx.y * gx + blockIdx.x;
  const int wg = (P & 7) * (nwg >> 3) + (P >> 3);
  const int m0 = (wg / gx) * 256, n0 = (wg % gx) * 256;

  const int Kspl = K / KS;
  const int kbeg = blockIdx.z * Kspl;
  const int NT = Kspl / TBK;                    // >= 8 for all our shapes

  // staging: per thread 4 gloads/tile (A q0,q1 + B q0,q1), 16 B each.
  // LDS dest linear (wave-uniform base + lane*16); source pre-inverse-swizzled.
  const short* srcA[2]; const short* srcB[2]; int ldso[2];
  #pragma unroll
  for (int q = 0; q < 2; ++q){
    int o = q*8192 + t*16;                      // byte offset within 16 KB half
    int row = o >> 6;                           // 64 B per row (32 bf16)
    int chunk = ((o >> 4) & 3) ^ ((row >> 1) & 3);
    ldso[q] = o;
    srcA[q] = A  + (size_t)(m0 + row) * K + kbeg + chunk * 8;
    srcB[q] = BT + (size_t)(n0 + row) * K + kbeg + chunk * 8;
  }

  // swizzled read offsets (shorts): slot = lk ^ ((row>>1)&3)  [rule #21 pair]
  int aoff[8], boff[4];
  #pragma unroll
  for (int m = 0; m < 8; ++m){
    int row = wr*128 + m*16 + lrow;
    aoff[m] = row*32 + (lk ^ ((row >> 1) & 3))*8;
  }
  #pragma unroll
  for (int n = 0; n < 4; ++n){
    int row = wc*64 + n*16 + lrow;
    boff[n] = 8192 + row*32 + (lk ^ ((row >> 1) & 3))*8;
  }

  auto stage = [&](int tile){
    const int s = tile & 3;
    const int ko = tile * TBK;
    #pragma unroll
    for (int q = 0; q < 2; ++q){
      gload_lds16(srcA[q] + ko, (char*)&lds[s][0] + ldso[q]);
      gload_lds16(srcB[q] + ko, (char*)&lds[s][0] + 16384 + ldso[q]);
    }
  };

  f32x4 acc[8][4] = {};

  stage(0);
  stage(1);
  for (int tt = 0; tt < NT; ++tt){
    // counted drain: newest 4 loads (tile tt+1) may stay in flight; tile tt done.
    if (tt < NT - 1) asm volatile("s_waitcnt vmcnt(4)" ::: "memory");
    else             asm volatile("s_waitcnt vmcnt(0)" ::: "memory");
    __builtin_amdgcn_s_barrier();               // all waves' contributions landed
    __builtin_amdgcn_sched_barrier(0);

    if (tt + 2 < NT) stage(tt + 2);             // into slot (tt+2)&3: 2 barriers stale

    const short* lp = &lds[tt & 3][0];
    s16x8 afr[8], bfr[4];
    #pragma unroll
    for (int n = 0; n < 4; ++n) bfr[n] = *(const s16x8*)(lp + boff[n]);
    #pragma unroll
    for (int m = 0; m < 8; ++m) afr[m] = *(const s16x8*)(lp + aoff[m]);

    asm volatile("s_waitcnt lgkmcnt(0)" ::: "memory");
    __builtin_amdgcn_sched_barrier(0);          // rule #18: pin MFMA after the wait
    __builtin_amdgcn_s_setprio(1);
    #pragma unroll
    for (int m = 0; m < 8; ++m)
      #pragma unroll
      for (int n = 0; n < 4; ++n)
        acc[m][n] = __builtin_amdgcn_mfma_f32_16x16x32_bf16(afr[m], bfr[n], acc[m][n], 0, 0, 0);
    __builtin_amdgcn_s_setprio(0);
  }

  void* pz = (blockIdx.z == 0) ? o0 : (blockIdx.z == 1) ? o1
           : (blockIdx.z == 2) ? o2 : o3;
  #pragma unroll
  for (int m = 0; m < 8; ++m){
    #pragma unroll
    for (int n = 0; n < 4; ++n){
      #pragma unroll
      for (int r = 0; r < 4; ++r){
        int row = m0 + wr*128 + m*16 + lk*4 + r;   // C/D: row=(lane>>4)*4+reg
        int col = n0 + wc*64  + n*16 + lrow;       //      col=lane&15
        size_t idx = (size_t)row * N + col;
        if (EPI == 4){
          ((short*)pz)[idx] = f2bf(acc[m][n][r]);
        } else {
          float v = acc[m][n][r] + bias[col];
          if (EPI == 0){
            ((short*)o0)[idx] = f2bf(v);
          } else {
            float g = 0.5f * v * (1.0f + erff(v * 0.70710678118654752f));
            ((short*)o0)[idx] = f2bf(g);
          }
        }
      }
    }
  }
}

// ---------------- flash attention (causal), LDS-staged K/V, paired q-tiles --
// 512 blocks, 1-D grid, decoded so all 16 q-tile blocks of one (b,h) land on
// the same XCD (P%8 constant) -> K/V stay resident in that XCD's L2.
__global__ __launch_bounds__(256, 2) void attn_kernel(
    const short* __restrict__ qkv, const short* __restrict__ vt,
    short* __restrict__ ob)
{
  const int P = blockIdx.x;
  const int xcd = P & 7;
  const int idx = P >> 3;
  const int pairi = idx & 15;           // 0..15
  const int bh = xcd + ((idx >> 4) << 3);
  const int b = bh >> 4, h = bh & 15;
  const int t  = threadIdx.x;
  const int lane = t & 63;
  const int w = t >> 6;
  const int lrow = lane & 15, lk = lane >> 4;

  __shared__ short sK[2][64*64];        // 2 x 8 KB, rows of 64 shorts, XOR-swizzled
  __shared__ short sV[2][64*64];        // 2 x 8 KB
  __shared__ short sP[4][16][68];       // per-wave P tile, +4 shorts pad

  const size_t kgbase = (size_t)(b*2048)*3072 + 1024 + h*64;   // K rows in qkv
  const size_t vgbase = (size_t)((b*16 + h)*64)*2048;          // V^T rows in vt

  auto stage = [&](int buf, int k0){
    #pragma unroll
    for (int r2 = 0; r2 < 2; ++r2){     // 8 KB per tile: 2 rounds x 4 KB
      int o = r2*4096 + t*16;           // linear LDS byte offset
      int row = o >> 7;                 // 128 B per row
      int lsl = ((o >> 4) & 7) ^ (row & 7);   // inverse-swizzled source chunk
      gload_lds16(qkv + kgbase + (size_t)(k0 + row)*3072 + lsl*8, (char*)sK[buf] + o);
      gload_lds16(vt  + vgbase + (size_t)row*2048 + k0   + lsl*8, (char*)sV[buf] + o);
    }
  };

  for (int pass = 0; pass < 2; ++pass){
    const int qt = pass ? 31 - pairi : pairi;
    const int q0 = qt * 64;
    const int qbase = q0 + w * 16;

    s16x8 aq[2];
    #pragma unroll
    for (int kc = 0; kc < 2; ++kc)
      aq[kc] = *(const s16x8*)(qkv + (size_t)(b*2048 + qbase + lrow)*3072 + h*64 + kc*32 + lk*8);

    f32x4 oacc[4] = {};
    float mrun[4], lrun[4];
    #pragma unroll
    for (int r = 0; r < 4; ++r){ mrun[r] = -1e30f; lrun[r] = 0.0f; }

    const int nt = qt + 1;
    __syncthreads();                    // prior pass's reads complete
    stage(0, 0);
    __syncthreads();
    int cur = 0;

    for (int ktile = 0; ktile < nt; ++ktile){
      const int k0 = ktile * 64;
      if (ktile + 1 < nt) stage(cur ^ 1, k0 + 64);   // prefetch next tile

      f32x4 sacc[4] = {};
      __builtin_amdgcn_s_setprio(1);
      #pragma unroll
      for (int kc = 0; kc < 2; ++kc){
        #pragma unroll
        for (int ct = 0; ct < 4; ++ct){
          int row = ct*16 + lrow;
          int slot = (kc*4 + lk) ^ (row & 7);
          s16x8 bk = *(const s16x8*)&sK[cur][row*64 + slot*8];
          sacc[ct] = __builtin_amdgcn_mfma_f32_16x16x32_bf16(aq[kc], bk, sacc[ct], 0, 0, 0);
        }
      }
      __builtin_amdgcn_s_setprio(0);

      float s[4][4];
      const bool need_mask = (k0 + 63 > qbase);
      #pragma unroll
      for (int ct = 0; ct < 4; ++ct){
        #pragma unroll
        for (int r = 0; r < 4; ++r){
          float v = sacc[ct][r] * 0.125f;               // 1/sqrt(64)
          if (need_mask){
            int qi = qbase + lk*4 + r;
            int ki = k0 + ct*16 + lrow;
            if (ki > qi) v = -10000.0f;
          }
          s[ct][r] = v;
        }
      }

      #pragma unroll
      for (int r = 0; r < 4; ++r){
        float mx = fmaxf(fmaxf(s[0][r], s[1][r]), fmaxf(s[2][r], s[3][r]));
        #pragma unroll
        for (int off = 1; off < 16; off <<= 1)
          mx = fmaxf(mx, __shfl_xor(mx, off, 64));
        float mnew = fmaxf(mrun[r], mx);
        float sf = __expf(mrun[r] - mnew);
        lrun[r] *= sf;
        #pragma unroll
        for (int dt = 0; dt < 4; ++dt) oacc[dt][r] *= sf;
        float ts = 0.0f;
        #pragma unroll
        for (int ct = 0; ct < 4; ++ct){
          float p = __expf(s[ct][r] - mnew);
          s[ct][r] = p;
          ts += p;
        }
        #pragma unroll
        for (int off = 1; off < 16; off <<= 1)
          ts += __shfl_xor(ts, off, 64);
        lrun[r] += ts;
        mrun[r] = mnew;
      }

      #pragma unroll
      for (int ct = 0; ct < 4; ++ct)
        #pragma unroll
        for (int r = 0; r < 4; ++r)
          sP[w][lk*4 + r][ct*16 + lrow] = f2bf(s[ct][r]);

      s16x8 pa[2];
      #pragma unroll
      for (int kc = 0; kc < 2; ++kc)
        pa[kc] = *(const s16x8*)&sP[w][lrow][kc*32 + lk*8];
      __builtin_amdgcn_s_setprio(1);
      #pragma unroll
      for (int dt = 0; dt < 4; ++dt){
        #pragma unroll
        for (int kc = 0; kc < 2; ++kc){
          int row = dt*16 + lrow;
          int slot = (kc*4 + lk) ^ (row & 7);
          s16x8 bv = *(const s16x8*)&sV[cur][row*64 + slot*8];
          oacc[dt] = __builtin_amdgcn_mfma_f32_16x16x32_bf16(pa[kc], bv, oacc[dt], 0, 0, 0);
        }
      }
      __builtin_amdgcn_s_setprio(0);

      __syncthreads();
      cur ^= 1;
    }

    #pragma unroll
    for (int r = 0; r < 4; ++r){
      float inv = 1.0f / lrun[r];
      int row = b*2048 + qbase + lk*4 + r;
      #pragma unroll
      for (int dt = 0; dt < 4; ++dt){
        int col = h*64 + dt*16 + lrow;
        ob[(size_t)row * 1024 + col] = f2bf(oacc[dt][r] * inv);
      }
    }
  }
}

// -------- LN fused with split-K4 reduce + residual --------------------------
// v = p0+p1+p2+p3 (bf16 partials) + bias + (resid_bf | resid_f); out = LN(v)
__global__ __launch_bounds__(256) void ln_fused(
    const short* __restrict__ p0, const short* __restrict__ p1,
    const short* __restrict__ p2, const short* __restrict__ p3,
    const float* __restrict__ bias,
    const short* __restrict__ resid_bf, const float* __restrict__ resid_f,
    const float* __restrict__ g, const float* __restrict__ b,
    void* __restrict__ out, int bf16_out)
{
  const int row = blockIdx.x;
  const int t = threadIdx.x;
  const size_t base = (size_t)row*1024 + t*4;
  short4 a0 = *(const short4*)(p0 + base);
  short4 a1 = *(const short4*)(p1 + base);
  short4 a2 = *(const short4*)(p2 + base);
  short4 a3 = *(const short4*)(p3 + base);
  float4 bi = *(const float4*)(bias + t*4);
  float r0, r1, r2, r3;
  if (resid_bf){
    short4 rr = *(const short4*)(resid_bf + base);
    r0 = bf2f(rr.x); r1 = bf2f(rr.y); r2 = bf2f(rr.z); r3 = bf2f(rr.w);
  } else {
    float4 rr = *(const float4*)(resid_f + base);
    r0 = rr.x; r1 = rr.y; r2 = rr.z; r3 = rr.w;
  }
  float v0 = bf2f(a0.x) + bf2f(a1.x) + bf2f(a2.x) + bf2f(a3.x) + bi.x + r0;
  float v1 = bf2f(a0.y) + bf2f(a1.y) + bf2f(a2.y) + bf2f(a3.y) + bi.y + r1;
  float v2 = bf2f(a0.z) + bf2f(a1.z) + bf2f(a2.z) + bf2f(a3.z) + bi.z + r2;
  float v3 = bf2f(a0.w) + bf2f(a1.w) + bf2f(a2.w) + bf2f(a3.w) + bi.w + r3;
  float s = v0 + v1 + v2 + v3;
  float q = v0*v0 + v1*v1 + v2*v2 + v3*v3;
  #pragma unroll
  for (int off = 1; off < 64; off <<= 1){
    s += __shfl_xor(s, off, 64);
    q += __shfl_xor(q, off, 64);
  }
  __shared__ float ss[4], sq[4];
  if ((t & 63) == 0){ ss[t >> 6] = s; sq[t >> 6] = q; }
  __syncthreads();
  s = ss[0] + ss[1] + ss[2] + ss[3];
  q = sq[0] + sq[1] + sq[2] + sq[3];
  float mu = s * (1.0f/1024.0f);
  float var = q * (1.0f/1024.0f) - mu*mu;
  float rs = rsqrtf(var + 1e-5f);
  float4 gg = *(const float4*)(g + t*4);
  float4 bb = *(const float4*)(b + t*4);
  float o0 = (v0 - mu)*rs*gg.x + bb.x;
  float o1 = (v1 - mu)*rs*gg.y + bb.y;
  float o2 = (v2 - mu)*rs*gg.z + bb.z;
  float o3 = (v3 - mu)*rs*gg.w + bb.w;
  if (bf16_out){
    short4 o; o.x = f2bf(o0); o.y = f2bf(o1); o.z = f2bf(o2); o.w = f2bf(o3);
    *(short4*)((short*)out + base) = o;
  } else {
    float4 o = {o0, o1, o2, o3};
    *(float4*)((float*)out + base) = o;
  }
}

// ---------------------------------------------------------------------------
extern "C" void kernel_launch(void* const* d_in, const int* in_sizes, int n_in,
                              void* d_out, int out_size, void* d_ws, size_t ws_size,
                              hipStream_t stream) {
  const float* x      = (const float*)d_in[0];
  const float* w_attn = (const float*)d_in[1];
  const float* b_attn = (const float*)d_in[2];
  const float* w_o    = (const float*)d_in[3];
  const float* b_o    = (const float*)d_in[4];
  const float* ln1_g  = (const float*)d_in[5];
  const float* ln1_b  = (const float*)d_in[6];
  const float* w_fc   = (const float*)d_in[7];
  const float* b_fc   = (const float*)d_in[8];
  const float* w_pr   = (const float*)d_in[9];
  const float* b_pr   = (const float*)d_in[10];
  const float* ln2_g  = (const float*)d_in[11];
  const float* ln2_b  = (const float*)d_in[12];

  char* ws = (char*)d_ws;
  const size_t MB = 1048576;
  // lifetimes: high-water 96 MiB
  short* waT  = (short*)(ws + 0);          // 6 MiB  (steps 2-6)
  short* wfT  = (short*)(ws + 6*MB);       // 8 MiB  (steps 2-11)
  short* wpT  = (short*)(ws + 14*MB);      // 8 MiB  (steps 2-12)
  short* woT  = (short*)(ws + 22*MB);      // 2 MiB  (steps 2-9)
  short* xb   = (short*)(ws + 24*MB);      // 8 MiB  (steps 1-6)
  short* vt   = (short*)(ws + 24*MB);      // 8 MiB  (steps 7-8)
  short* pp2  = (short*)(ws + 24*MB);      // 8 MiB  (steps 9-10, 12-13)
  short* qkvb = (short*)(ws + 32*MB);      // 24 MiB (steps 6-8)
  short* fb   = (short*)(ws + 32*MB);      // 32 MiB (steps 11-12)
  short* ob   = (short*)(ws + 56*MB);      // 8 MiB  (steps 8-9)
  short* pp0  = (short*)(ws + 64*MB);      // 8 MiB  (steps 9-10, 12-13)
  short* pp1  = (short*)(ws + 72*MB);      // 8 MiB
  short* nb   = (short*)(ws + 80*MB);      // 8 MiB  (steps 10-13)
  short* pp3  = (short*)(ws + 88*MB);      // 8 MiB  (steps 9-10, 12-13)

  const int M = 4096;

  // 1. x -> bf16
  cvt_f32_bf16<<<dim3(M*1024/1024), dim3(256), 0, stream>>>(x, xb, M*1024);
  // 2-5. weight transposes (f32 [K][N] -> bf16 [N][K])
  wtrans<<<dim3(3072/32, 1024/32), dim3(32,8), 0, stream>>>(w_attn, waT, 1024, 3072);
  wtrans<<<dim3(1024/32, 1024/32), dim3(32,8), 0, stream>>>(w_o,   woT, 1024, 1024);
  wtrans<<<dim3(4096/32, 1024/32), dim3(32,8), 0, stream>>>(w_fc,  wfT, 1024, 4096);
  wtrans<<<dim3(1024/32, 4096/32), dim3(32,8), 0, stream>>>(w_pr,  wpT, 4096, 1024);
  // 6. qkv = x @ w_attn + b_attn  (bf16 out); grid 12x16 = 192 blocks
  gemm256<<<dim3(3072/256, M/256, 1), dim3(512), 0, stream>>>(
      xb, waT, b_attn, qkvb, nullptr, nullptr, nullptr, M, 3072, 1024, 0, 1);
  // 7. vt = transpose of V per (b,h)
  vtrans<<<dim3(2048/32, 64/32, 32), dim3(32,8), 0, stream>>>(qkvb, vt);
  // 8. attention -> ob (bf16)
  attn_kernel<<<dim3(512), dim3(256), 0, stream>>>(qkvb, vt, ob);
  // 9. o-proj split-K4: pp0..3 = ob @ w_o partials (bf16); 4x16x4 = 256 blocks
  gemm256<<<dim3(1024/256, M/256, 4), dim3(512), 0, stream>>>(
      ob, woT, nullptr, pp0, pp1, pp2, pp3, M, 1024, 1024, 4, 4);
  // 10. n = LN(pp* + b_o + x) -> nb (bf16)   [r1 eliminated]
  ln_fused<<<dim3(M), dim3(256), 0, stream>>>(pp0, pp1, pp2, pp3, b_o,
                                              nullptr, x, ln1_g, ln1_b, nb, 1);
  // 11. f = gelu(n @ w_fc + b_fc) -> fb (bf16); 16x16 = 256 blocks
  gemm256<<<dim3(4096/256, M/256, 1), dim3(512), 0, stream>>>(
      nb, wfT, b_fc, fb, nullptr, nullptr, nullptr, M, 4096, 1024, 2, 1);
  // 12. r2 split-K4: pp0..3 = fb @ w_pr partials (bf16); 4x16x4 = 256 blocks
  gemm256<<<dim3(1024/256, M/256, 4), dim3(512), 0, stream>>>(
      fb, wpT, nullptr, pp0, pp1, pp2, pp3, M, 1024, 4096, 4, 4);
  // 13. h = LN(pp* + b_pr + nb) -> d_out (f32)
  ln_fused<<<dim3(M), dim3(256), 0, stream>>>(pp0, pp1, pp2, pp3, b_pr,
                                              nb, nullptr, ln2_g, ln2_b, d_out, 0);
}